// Round 13
// baseline (174.692 us; speedup 1.0000x reference)
//
#include <hip/hip_runtime.h>
#include <cstddef>

// Problem constants (hard-coded from reference):
// D=256, NH=8, NL=4, NP=4, DH=32, B=4, LV=5440, DFF=1024
// SHAPES = {64,64},{32,32},{16,16},{8,8}; level_start = {0,4096,5120,5376}
#define LVTOT  5440
#define MROWS  (4 * LVTOT)   // 21760 = 128 * 170 = 64 * 340

typedef __attribute__((ext_vector_type(8))) short short8;
typedef __attribute__((ext_vector_type(4))) float floatx4;

static __device__ __forceinline__ unsigned short f2bf(float f) {
    union { float f; unsigned int u; } v; v.f = f;
    unsigned int u = v.u;
    return (unsigned short)((u + 0x7FFFu + ((u >> 16) & 1u)) >> 16);   // RNE
}
static __device__ __forceinline__ float bf2f(unsigned short u) {
    union { unsigned int u; float f; } v; v.u = ((unsigned int)u) << 16; return v.f;
}
static __device__ __forceinline__ float bf2fs(short s) { return bf2f((unsigned short)s); }

// ---------------------------------------------------------------------------
// One-shot weight prep, all f32 [K][N] -> bf16 [N][K] at fixed slots:
//   val[0,65536) oa[65536,163840) (off rows 0..255 + attn rows 256..383)
//   out[163840,229376) ff1[229376,491520) ff2[491520,753664)
// plus bias_oa[384] floats (b_off ++ b_attn). Grid 2946x256.
// ---------------------------------------------------------------------------
__global__ __launch_bounds__(256) void prep_weights(
    const float* __restrict__ Wv, const float* __restrict__ Wo,
    const float* __restrict__ Wa, const float* __restrict__ Wu,
    const float* __restrict__ W1, const float* __restrict__ W2,
    const float* __restrict__ bo, const float* __restrict__ ba,
    unsigned short* __restrict__ wt, float* __restrict__ bias_oa)
{
    int idx = blockIdx.x * 256 + threadIdx.x;
    if (idx >= 754048) return;
    if (idx >= 753664) {               // bias concat
        int j = idx - 753664;
        bias_oa[j] = (j < 256) ? bo[j] : ba[j - 256];
        return;
    }
    float src;
    if (idx < 65536) {
        int r = idx; src = Wv[(size_t)(r & 255) * 256 + (r >> 8)];
    } else if (idx < 163840) {
        int r = idx - 65536; int n = r >> 8, k = r & 255;
        src = (n < 256) ? Wo[(size_t)k * 256 + n] : Wa[(size_t)k * 128 + (n - 256)];
    } else if (idx < 229376) {
        int r = idx - 163840; src = Wu[(size_t)(r & 255) * 256 + (r >> 8)];
    } else if (idx < 491520) {
        int r = idx - 229376; src = W1[(size_t)(r & 255) * 1024 + (r >> 8)];
    } else {
        int r = idx - 491520; src = W2[(size_t)(r & 1023) * 256 + (r >> 10)];
    }
    wt[idx] = f2bf(src);
}

// ---------------------------------------------------------------------------
// Reg-staged MFMA GEMM, padded LDS (conflict-free), 4 waves (2x2), BK=64.
// 64x64 tiles -> 18.4 KB LDS -> ~8 blocks/CU resident (TLP hides the
// stage->barrier->compute latency chain; proven R12: GEMMs left top-5).
// SWZ=1: XCD-aware bijective remap (m204) + bn-fast tile order -> A-panel
// stays hot in one XCD's L2 (FETCH 44->7.8 MB in R11).
// ---------------------------------------------------------------------------
template<int AF32, int BM, int BN, int SPLITK, int RELU, int SWZ>
__global__ __launch_bounds__(256) void gemm_rs(
    const void* __restrict__ Av, const unsigned short* __restrict__ Bt,
    const float* __restrict__ bias,
    float* __restrict__ C, unsigned short* __restrict__ Cbf,
    int M, int N, int K)
{
    constexpr int AI = BM / 32;
    constexpr int BI = BN / 32;
    constexpr int FM = BM / 32;
    constexpr int FN = BN / 32;

    __shared__ short As[BM][72];
    __shared__ short Bs[BN][72];

    const int tid  = threadIdx.x;
    const int wave = tid >> 6;
    const int lane = tid & 63;
    const int ntiles = N / BN;

    int wgid;
    if (SWZ) {
        const int nwg = gridDim.x;
        const int xcd = blockIdx.x & 7;
        const int t   = blockIdx.x >> 3;
        const int q = nwg >> 3, r = nwg & 7;
        wgid = (xcd < r ? xcd * (q + 1) : r * (q + 1) + (xcd - r) * q) + t;
    } else {
        wgid = blockIdx.x;
    }
    const int tpm = ntiles * SPLITK;
    const int bm  = wgid / tpm;
    const int rem = wgid % tpm;
    const int bn  = rem % ntiles;
    const int ks  = rem / ntiles;

    const int row0 = bm * BM;
    const int col0 = bn * BN;
    const int Kper = K / SPLITK;
    const int kbeg = ks * Kper;

    const int wm = (wave >> 1) * (BM / 2);
    const int wn = (wave & 1) * (BN / 2);

    floatx4 acc[FM][FN];
    #pragma unroll
    for (int i = 0; i < FM; ++i)
        #pragma unroll
        for (int j = 0; j < FN; ++j)
            acc[i][j] = (floatx4){0.f, 0.f, 0.f, 0.f};

    const int lr = tid >> 3;
    const int lc = tid & 7;

    for (int k0 = 0; k0 < Kper; k0 += 64) {
        #pragma unroll
        for (int i = 0; i < AI; ++i) {
            const int r = lr + i * 32;
            if (AF32) {
                const float* Af = (const float*)Av;
                const float4 v0 = *reinterpret_cast<const float4*>(
                    &Af[(size_t)(row0 + r) * K + kbeg + k0 + lc * 8]);
                const float4 v1 = *reinterpret_cast<const float4*>(
                    &Af[(size_t)(row0 + r) * K + kbeg + k0 + lc * 8 + 4]);
                short8 s;
                s[0] = (short)f2bf(v0.x); s[1] = (short)f2bf(v0.y);
                s[2] = (short)f2bf(v0.z); s[3] = (short)f2bf(v0.w);
                s[4] = (short)f2bf(v1.x); s[5] = (short)f2bf(v1.y);
                s[6] = (short)f2bf(v1.z); s[7] = (short)f2bf(v1.w);
                *reinterpret_cast<short8*>(&As[r][lc * 8]) = s;
            } else {
                const unsigned short* Ab = (const unsigned short*)Av;
                *reinterpret_cast<short8*>(&As[r][lc * 8]) =
                    *reinterpret_cast<const short8*>(
                        &Ab[(size_t)(row0 + r) * K + kbeg + k0 + lc * 8]);
            }
        }
        #pragma unroll
        for (int i = 0; i < BI; ++i) {
            const int r = lr + i * 32;
            *reinterpret_cast<short8*>(&Bs[r][lc * 8]) =
                *reinterpret_cast<const short8*>(
                    &Bt[(size_t)(col0 + r) * K + kbeg + k0 + lc * 8]);
        }
        __syncthreads();

        #pragma unroll
        for (int kk = 0; kk < 64; kk += 32) {
            short8 af[FM], bfr[FN];
            #pragma unroll
            for (int i = 0; i < FM; ++i)
                af[i] = *reinterpret_cast<const short8*>(
                    &As[wm + i * 16 + (lane & 15)][kk + (lane >> 4) * 8]);
            #pragma unroll
            for (int j = 0; j < FN; ++j)
                bfr[j] = *reinterpret_cast<const short8*>(
                    &Bs[wn + j * 16 + (lane & 15)][kk + (lane >> 4) * 8]);
            #pragma unroll
            for (int i = 0; i < FM; ++i)
                #pragma unroll
                for (int j = 0; j < FN; ++j)
                    acc[i][j] = __builtin_amdgcn_mfma_f32_16x16x32_bf16(
                        af[i], bfr[j], acc[i][j], 0, 0, 0);
        }
        __syncthreads();
    }

    float* Cp = C ? C + (size_t)ks * M * N : nullptr;
    const int rbase = row0 + wm + (lane >> 4) * 4;
    const int cbase = col0 + wn + (lane & 15);
    #pragma unroll
    for (int j = 0; j < FN; ++j) {
        const float bj = (SPLITK == 1 || ks == 0) ? bias[cbase + j * 16] : 0.f;
        #pragma unroll
        for (int i = 0; i < FM; ++i) {
            #pragma unroll
            for (int r = 0; r < 4; ++r) {
                float v = acc[i][j][r] + bj;
                if (RELU) v = fmaxf(v, 0.f);
                const size_t idx = (size_t)(rbase + i * 16 + r) * N + cbase + j * 16;
                if (Cp)  Cp[idx] = v;
                if (Cbf) Cbf[idx] = f2bf(v);
            }
        }
    }
}

// ---------------------------------------------------------------------------
// Deformable sampling + fused softmax, 2-phase LDS-staged.
// R13: 32 units/block (meta 16.9 KB -> 8 blocks/CU, 100% wave cap) and
// 8 lanes/unit in phase 2 (4 channels each, 8B gathers) — double the
// resident parallelism so gather latency overlaps VALU.
// Phase 1 (tid<128): lane = unit*4+level, softmax + 16 corners -> meta.
// Phase 2: lane = unit*8+chunk, 64 x 8B gathers, no cross-lane reduce.
// ---------------------------------------------------------------------------
__global__ __launch_bounds__(256) void msda_sample(
    const unsigned short* __restrict__ vproj,
    const unsigned short* __restrict__ oa,
    const float* __restrict__ refs,
    unsigned short* __restrict__ outbf)
{
    __shared__ uint4 meta[32][33];   // row stride 528B: 2-way reads (free)

    const int tid = threadIdx.x;

    // ---------------- phase 1: coords (32 units x 4 levels = 128 lanes)
    if (tid < 128) {
        const int ul = tid >> 2;
        const int u  = (blockIdx.x << 5) + ul;
        const int h  = u & 7;
        const int bq = u >> 3;
        const int l   = tid & 3;
        const int sl  = 6 - l;
        const int Nl  = 1 << sl;
        const int msk = Nl - 1;
        const int lsi = (l == 0) ? 0 : (l == 1) ? 4096 : (l == 2) ? 5120 : 5376;

        const size_t oabase = (size_t)bq * 384;
        const short8  offv = *reinterpret_cast<const short8*>(oa + oabase + h * 32 + l * 8);
        const ushort4 lgu  = *reinterpret_cast<const ushort4*>(oa + oabase + 256 + h * 16 + l * 4);
        const float2  rr   = *reinterpret_cast<const float2*>(refs + (size_t)bq * 8 + l * 2);

        float lg0 = bf2f(lgu.x), lg1 = bf2f(lgu.y), lg2 = bf2f(lgu.z), lg3 = bf2f(lgu.w);
        float m = fmaxf(fmaxf(lg0, lg1), fmaxf(lg2, lg3));
        m = fmaxf(m, __shfl_xor(m, 1));
        m = fmaxf(m, __shfl_xor(m, 2));
        float e0 = __expf(lg0 - m), e1 = __expf(lg1 - m),
              e2 = __expf(lg2 - m), e3 = __expf(lg3 - m);
        float s = e0 + e1 + e2 + e3;
        s += __shfl_xor(s, 1);
        s += __shfl_xor(s, 2);
        const float inv = 1.f / s;
        const float aw4[4] = {e0 * inv, e1 * inv, e2 * inv, e3 * inv};

        const float Nf = (float)Nl;
        #pragma unroll
        for (int p = 0; p < 4; ++p) {
            const float ox = bf2fs(offv[p * 2 + 0]);
            const float oy = bf2fs(offv[p * 2 + 1]);
            const float aw = aw4[p];
            const float x = fmaf(rr.x, Nf, ox) - 0.5f;
            const float y = fmaf(rr.y, Nf, oy) - 0.5f;
            const float xf = floorf(x), yf = floorf(y);
            const float tx = x - xf, ty = y - yf;
            const int xi = (int)xf, yi = (int)yf;
            const bool x0v = (unsigned)xi < (unsigned)Nl;
            const bool x1v = (unsigned)(xi + 1) < (unsigned)Nl;
            const bool y0v = (unsigned)yi < (unsigned)Nl;
            const bool y1v = (unsigned)(yi + 1) < (unsigned)Nl;
            const float w0x = (1.f - tx) * aw, w1x = tx * aw;
            const int xm0 = xi & msk, xm1 = (xi + 1) & msk;
            const int ym0 = (yi & msk) << sl, ym1 = ((yi + 1) & msk) << sl;
            uint4 m0, m1;
            m0.x = (unsigned)((lsi + (ym0 | xm0)) << 9);   // byte offset (*512)
            m0.y = __float_as_uint((x0v & y0v) ? w0x * (1.f - ty) : 0.f);
            m0.z = (unsigned)((lsi + (ym0 | xm1)) << 9);
            m0.w = __float_as_uint((x1v & y0v) ? w1x * (1.f - ty) : 0.f);
            m1.x = (unsigned)((lsi + (ym1 | xm0)) << 9);
            m1.y = __float_as_uint((x0v & y1v) ? w0x * ty : 0.f);
            m1.z = (unsigned)((lsi + (ym1 | xm1)) << 9);
            m1.w = __float_as_uint((x1v & y1v) ? w1x * ty : 0.f);
            meta[ul][l * 8 + p * 2 + 0] = m0;
            meta[ul][l * 8 + p * 2 + 1] = m1;
        }
    }
    __syncthreads();

    // ---------------- phase 2: gather + MAC (32 units x 8 chunks)
    const int ul = tid >> 3;
    const int c  = tid & 7;          // 4-channel chunk
    const int u  = (blockIdx.x << 5) + ul;
    const int h  = u & 7;
    const int bq = u >> 3;
    const int b  = bq / LVTOT;
    const unsigned short* vb = vproj + (size_t)b * (LVTOT * 256) + h * 32 + c * 4;

    float acc[4] = {0.f, 0.f, 0.f, 0.f};
    #pragma unroll 4
    for (int j = 0; j < 32; ++j) {
        const uint4 mt = meta[ul][j];
        const uint2 g0 = *reinterpret_cast<const uint2*>((const char*)vb + mt.x);
        const uint2 g1 = *reinterpret_cast<const uint2*>((const char*)vb + mt.z);
        const float w0 = __uint_as_float(mt.y);
        const float w1 = __uint_as_float(mt.w);
        acc[0] = fmaf(w0, __uint_as_float(g0.x << 16), acc[0]);
        acc[1] = fmaf(w0, __uint_as_float(g0.x & 0xffff0000u), acc[1]);
        acc[2] = fmaf(w0, __uint_as_float(g0.y << 16), acc[2]);
        acc[3] = fmaf(w0, __uint_as_float(g0.y & 0xffff0000u), acc[3]);
        acc[0] = fmaf(w1, __uint_as_float(g1.x << 16), acc[0]);
        acc[1] = fmaf(w1, __uint_as_float(g1.x & 0xffff0000u), acc[1]);
        acc[2] = fmaf(w1, __uint_as_float(g1.y << 16), acc[2]);
        acc[3] = fmaf(w1, __uint_as_float(g1.y & 0xffff0000u), acc[3]);
    }

    uint2 ov;
    ov.x = (unsigned)f2bf(acc[0]) | ((unsigned)f2bf(acc[1]) << 16);
    ov.y = (unsigned)f2bf(acc[2]) | ((unsigned)f2bf(acc[3]) << 16);
    *reinterpret_cast<uint2*>(outbf + (size_t)bq * 256 + h * 32 + c * 4) = ov;
}

// ---------------------------------------------------------------------------
// LayerNorm over 256 with fused adds:
//   x = x1 + (x2?:0); y = LN(x)*g + b; out = (res?:0) + y; optional bf16 copy.
// ---------------------------------------------------------------------------
__global__ __launch_bounds__(256) void ln_fused(
    const float* __restrict__ x1, const float* __restrict__ x2,
    const float* __restrict__ res,
    const float* __restrict__ g, const float* __restrict__ bta,
    float* __restrict__ out, unsigned short* __restrict__ outbf)
{
    const int row  = (blockIdx.x << 2) + (threadIdx.x >> 6);
    const int lane = threadIdx.x & 63;
    const size_t base = (size_t)row * 256 + lane * 4;

    float4 v = *reinterpret_cast<const float4*>(&x1[base]);
    if (x2) {
        float4 u = *reinterpret_cast<const float4*>(&x2[base]);
        v.x += u.x; v.y += u.y; v.z += u.z; v.w += u.w;
    }
    float s1 = v.x + v.y + v.z + v.w;
    float s2 = v.x * v.x + v.y * v.y + v.z * v.z + v.w * v.w;
    #pragma unroll
    for (int s = 1; s < 64; s <<= 1) {
        s1 += __shfl_xor(s1, s);
        s2 += __shfl_xor(s2, s);
    }
    const float mu  = s1 * (1.f / 256.f);
    const float var = s2 * (1.f / 256.f) - mu * mu;
    const float rstd = rsqrtf(var + 1e-5f);

    float4 gg = *reinterpret_cast<const float4*>(&g[lane * 4]);
    float4 bb = *reinterpret_cast<const float4*>(&bta[lane * 4]);
    float4 o;
    o.x = (v.x - mu) * rstd * gg.x + bb.x;
    o.y = (v.y - mu) * rstd * gg.y + bb.y;
    o.z = (v.z - mu) * rstd * gg.z + bb.z;
    o.w = (v.w - mu) * rstd * gg.w + bb.w;
    if (res) {
        float4 r = *reinterpret_cast<const float4*>(&res[base]);
        o.x += r.x; o.y += r.y; o.z += r.z; o.w += r.w;
    }
    *reinterpret_cast<float4*>(&out[base]) = o;
    if (outbf) {
        ushort4 ob;
        ob.x = f2bf(o.x); ob.y = f2bf(o.y); ob.z = f2bf(o.z); ob.w = f2bf(o.w);
        reinterpret_cast<ushort4*>(outbf + base - lane * 4)[lane] = ob;
    }
}

// ---------------------------------------------------------------------------
extern "C" void kernel_launch(void* const* d_in, const int* in_sizes, int n_in,
                              void* d_out, int out_size, void* d_ws, size_t ws_size,
                              hipStream_t stream)
{
    const float* query  = (const float*)d_in[0];
    const float* refs   = (const float*)d_in[1];
    const float* value  = (const float*)d_in[2];
    const float* W_off  = (const float*)d_in[5];
    const float* b_off  = (const float*)d_in[6];
    const float* W_attn = (const float*)d_in[7];
    const float* b_attn = (const float*)d_in[8];
    const float* W_val  = (const float*)d_in[9];
    const float* b_val  = (const float*)d_in[10];
    const float* W_out  = (const float*)d_in[11];
    const float* b_out  = (const float*)d_in[12];
    const float* ln1g   = (const float*)d_in[13];
    const float* ln1b   = (const float*)d_in[14];
    const float* ln2g   = (const float*)d_in[15];
    const float* ln2b   = (const float*)d_in[16];
    const float* W_ff1  = (const float*)d_in[17];
    const float* b_ff1  = (const float*)d_in[18];
    const float* W_ff2  = (const float*)d_in[19];
    const float* b_ff2  = (const float*)d_in[20];
    float* out = (float*)d_out;
    float* ws  = (float*)d_ws;

    const size_t R = (size_t)MROWS * 256;   // 5,570,560 floats
    // Workspace (float offsets), lifetime-reused, total ~4.5R + 1.5MB:
    unsigned short* wt_base = (unsigned short*)ws;         // 753,664 bf16
    float* bias_oa = ws + 376832;                          // 384 (pad to 512)
    const size_t base0 = 377344;
    unsigned short* oa_bf    = (unsigned short*)(ws + base0);              // 0.75R fl
    unsigned short* vproj_bf = (unsigned short*)(ws + base0 + 3 * R / 4);  // 0.5R fl
    unsigned short* msda_bf  = (unsigned short*)(ws + base0 + 5 * R / 4);  // 0.5R fl
    // f1 pad: [base0+1.75R, base0+2R)
    float* tmp  = ws + base0 + 2 * R;                       // R
    float* qbuf = ws + base0 + 3 * R;                       // R
    unsigned short* qbuf_bf = (unsigned short*)(ws + base0 + 4 * R);       // 0.5R fl
    unsigned short* f1_bf = oa_bf;   // spans [base0, base0+2R) over dead regions

    unsigned short* wt_val = wt_base;
    unsigned short* wt_oa  = wt_base + 65536;
    unsigned short* wt_out = wt_base + 163840;
    unsigned short* wt_ff1 = wt_base + 229376;
    unsigned short* wt_ff2 = wt_base + 491520;

    const dim3 blk(256);
    const int mt64 = MROWS / 64;    // 340

    // 0: weight prep
    prep_weights<<<dim3(2946), blk, 0, stream>>>(W_val, W_off, W_attn, W_out,
                                                 W_ff1, W_ff2, b_off, b_attn,
                                                 wt_base, bias_oa);
    // 1: value projection (f32 A), 64x64 tiles -> 1360 blocks
    gemm_rs<1, 64, 64, 1, 0, 1><<<dim3(mt64 * 4), blk, 0, stream>>>(
        value, wt_val, b_val, nullptr, vproj_bf, MROWS, 256, 256);
    // 2: merged offsets+logits projection (f32 A), 64x64 -> 2040 blocks
    gemm_rs<1, 64, 64, 1, 0, 1><<<dim3(mt64 * 6), blk, 0, stream>>>(
        query, wt_oa, bias_oa, nullptr, oa_bf, MROWS, 384, 256);
    // 3: sampling (softmax fused; 32 units/block -> 5440 blocks)
    msda_sample<<<dim3(MROWS * 8 / 32), blk, 0, stream>>>(vproj_bf, oa_bf, refs, msda_bf);
    // 4: output projection, 64x64 -> 1360 blocks
    gemm_rs<0, 64, 64, 1, 0, 1><<<dim3(mt64 * 4), blk, 0, stream>>>(
        msda_bf, wt_out, b_out, tmp, nullptr, MROWS, 256, 256);
    // 5: q = value + LN(tmp); bf16 copy for FF1
    ln_fused<<<dim3(MROWS / 4), blk, 0, stream>>>(tmp, nullptr, value,
                                                  ln1g, ln1b, qbuf, qbuf_bf);
    // 6: f1 = relu(q @ W_ff1), 64x64 -> 5440 blocks
    gemm_rs<0, 64, 64, 1, 1, 1><<<dim3(mt64 * 16), blk, 0, stream>>>(
        qbuf_bf, wt_ff1, b_ff1, nullptr, f1_bf, MROWS, 1024, 256);
    // 7: f2 = f1 @ W_ff2, 64x64, K=1024 -> 1360 blocks
    gemm_rs<0, 64, 64, 1, 0, 1><<<dim3(mt64 * 4), blk, 0, stream>>>(
        f1_bf, wt_ff2, b_ff2, tmp, nullptr, MROWS, 256, 1024);
    // 8: out = LN(qbuf + tmp)
    ln_fused<<<dim3(MROWS / 4), blk, 0, stream>>>(qbuf, tmp, nullptr,
                                                  ln2g, ln2b, out, nullptr);
}

// Round 14
// 169.078 us; speedup vs baseline: 1.0332x; 1.0332x over previous
//
#include <hip/hip_runtime.h>
#include <cstddef>

// Problem constants (hard-coded from reference):
// D=256, NH=8, NL=4, NP=4, DH=32, B=4, LV=5440, DFF=1024
// SHAPES = {64,64},{32,32},{16,16},{8,8}; level_start = {0,4096,5120,5376}
#define LVTOT  5440
#define MROWS  (4 * LVTOT)   // 21760 = 128 * 170 = 64 * 340

typedef __attribute__((ext_vector_type(8))) short short8;
typedef __attribute__((ext_vector_type(4))) float floatx4;

static __device__ __forceinline__ unsigned short f2bf(float f) {
    union { float f; unsigned int u; } v; v.f = f;
    unsigned int u = v.u;
    return (unsigned short)((u + 0x7FFFu + ((u >> 16) & 1u)) >> 16);   // RNE
}
static __device__ __forceinline__ float bf2f(unsigned short u) {
    union { unsigned int u; float f; } v; v.u = ((unsigned int)u) << 16; return v.f;
}
static __device__ __forceinline__ float bf2fs(short s) { return bf2f((unsigned short)s); }

// ---------------------------------------------------------------------------
// One-shot weight prep, all f32 [K][N] -> bf16 [N][K] at fixed slots:
//   val[0,65536) oa[65536,163840) (off rows 0..255 + attn rows 256..383)
//   out[163840,229376) ff1[229376,491520) ff2[491520,753664)
// plus bias_oa[384] floats (b_off ++ b_attn). Grid 2946x256.
// ---------------------------------------------------------------------------
__global__ __launch_bounds__(256) void prep_weights(
    const float* __restrict__ Wv, const float* __restrict__ Wo,
    const float* __restrict__ Wa, const float* __restrict__ Wu,
    const float* __restrict__ W1, const float* __restrict__ W2,
    const float* __restrict__ bo, const float* __restrict__ ba,
    unsigned short* __restrict__ wt, float* __restrict__ bias_oa)
{
    int idx = blockIdx.x * 256 + threadIdx.x;
    if (idx >= 754048) return;
    if (idx >= 753664) {               // bias concat
        int j = idx - 753664;
        bias_oa[j] = (j < 256) ? bo[j] : ba[j - 256];
        return;
    }
    float src;
    if (idx < 65536) {
        int r = idx; src = Wv[(size_t)(r & 255) * 256 + (r >> 8)];
    } else if (idx < 163840) {
        int r = idx - 65536; int n = r >> 8, k = r & 255;
        src = (n < 256) ? Wo[(size_t)k * 256 + n] : Wa[(size_t)k * 128 + (n - 256)];
    } else if (idx < 229376) {
        int r = idx - 163840; src = Wu[(size_t)(r & 255) * 256 + (r >> 8)];
    } else if (idx < 491520) {
        int r = idx - 229376; src = W1[(size_t)(r & 255) * 1024 + (r >> 8)];
    } else {
        int r = idx - 491520; src = W2[(size_t)(r & 1023) * 256 + (r >> 10)];
    }
    wt[idx] = f2bf(src);
}

// ---------------------------------------------------------------------------
// Reg-staged MFMA GEMM, padded LDS (conflict-free), 4 waves (2x2), BK=64.
// 64x64 tiles -> 18.4 KB LDS -> ~8 blocks/CU resident (TLP hides the
// stage->barrier->compute latency chain; proven R12: GEMMs left top-5).
// SWZ=1: XCD-aware bijective remap (m204) + bn-fast tile order -> A-panel
// stays hot in one XCD's L2 (FETCH 44->7.8 MB in R11).
// ---------------------------------------------------------------------------
template<int AF32, int BM, int BN, int SPLITK, int RELU, int SWZ>
__global__ __launch_bounds__(256) void gemm_rs(
    const void* __restrict__ Av, const unsigned short* __restrict__ Bt,
    const float* __restrict__ bias,
    float* __restrict__ C, unsigned short* __restrict__ Cbf,
    int M, int N, int K)
{
    constexpr int AI = BM / 32;
    constexpr int BI = BN / 32;
    constexpr int FM = BM / 32;
    constexpr int FN = BN / 32;

    __shared__ short As[BM][72];
    __shared__ short Bs[BN][72];

    const int tid  = threadIdx.x;
    const int wave = tid >> 6;
    const int lane = tid & 63;
    const int ntiles = N / BN;

    int wgid;
    if (SWZ) {
        const int nwg = gridDim.x;
        const int xcd = blockIdx.x & 7;
        const int t   = blockIdx.x >> 3;
        const int q = nwg >> 3, r = nwg & 7;
        wgid = (xcd < r ? xcd * (q + 1) : r * (q + 1) + (xcd - r) * q) + t;
    } else {
        wgid = blockIdx.x;
    }
    const int tpm = ntiles * SPLITK;
    const int bm  = wgid / tpm;
    const int rem = wgid % tpm;
    const int bn  = rem % ntiles;
    const int ks  = rem / ntiles;

    const int row0 = bm * BM;
    const int col0 = bn * BN;
    const int Kper = K / SPLITK;
    const int kbeg = ks * Kper;

    const int wm = (wave >> 1) * (BM / 2);
    const int wn = (wave & 1) * (BN / 2);

    floatx4 acc[FM][FN];
    #pragma unroll
    for (int i = 0; i < FM; ++i)
        #pragma unroll
        for (int j = 0; j < FN; ++j)
            acc[i][j] = (floatx4){0.f, 0.f, 0.f, 0.f};

    const int lr = tid >> 3;
    const int lc = tid & 7;

    for (int k0 = 0; k0 < Kper; k0 += 64) {
        #pragma unroll
        for (int i = 0; i < AI; ++i) {
            const int r = lr + i * 32;
            if (AF32) {
                const float* Af = (const float*)Av;
                const float4 v0 = *reinterpret_cast<const float4*>(
                    &Af[(size_t)(row0 + r) * K + kbeg + k0 + lc * 8]);
                const float4 v1 = *reinterpret_cast<const float4*>(
                    &Af[(size_t)(row0 + r) * K + kbeg + k0 + lc * 8 + 4]);
                short8 s;
                s[0] = (short)f2bf(v0.x); s[1] = (short)f2bf(v0.y);
                s[2] = (short)f2bf(v0.z); s[3] = (short)f2bf(v0.w);
                s[4] = (short)f2bf(v1.x); s[5] = (short)f2bf(v1.y);
                s[6] = (short)f2bf(v1.z); s[7] = (short)f2bf(v1.w);
                *reinterpret_cast<short8*>(&As[r][lc * 8]) = s;
            } else {
                const unsigned short* Ab = (const unsigned short*)Av;
                *reinterpret_cast<short8*>(&As[r][lc * 8]) =
                    *reinterpret_cast<const short8*>(
                        &Ab[(size_t)(row0 + r) * K + kbeg + k0 + lc * 8]);
            }
        }
        #pragma unroll
        for (int i = 0; i < BI; ++i) {
            const int r = lr + i * 32;
            *reinterpret_cast<short8*>(&Bs[r][lc * 8]) =
                *reinterpret_cast<const short8*>(
                    &Bt[(size_t)(col0 + r) * K + kbeg + k0 + lc * 8]);
        }
        __syncthreads();

        #pragma unroll
        for (int kk = 0; kk < 64; kk += 32) {
            short8 af[FM], bfr[FN];
            #pragma unroll
            for (int i = 0; i < FM; ++i)
                af[i] = *reinterpret_cast<const short8*>(
                    &As[wm + i * 16 + (lane & 15)][kk + (lane >> 4) * 8]);
            #pragma unroll
            for (int j = 0; j < FN; ++j)
                bfr[j] = *reinterpret_cast<const short8*>(
                    &Bs[wn + j * 16 + (lane & 15)][kk + (lane >> 4) * 8]);
            #pragma unroll
            for (int i = 0; i < FM; ++i)
                #pragma unroll
                for (int j = 0; j < FN; ++j)
                    acc[i][j] = __builtin_amdgcn_mfma_f32_16x16x32_bf16(
                        af[i], bfr[j], acc[i][j], 0, 0, 0);
        }
        __syncthreads();
    }

    float* Cp = C ? C + (size_t)ks * M * N : nullptr;
    const int rbase = row0 + wm + (lane >> 4) * 4;
    const int cbase = col0 + wn + (lane & 15);
    #pragma unroll
    for (int j = 0; j < FN; ++j) {
        const float bj = (SPLITK == 1 || ks == 0) ? bias[cbase + j * 16] : 0.f;
        #pragma unroll
        for (int i = 0; i < FM; ++i) {
            #pragma unroll
            for (int r = 0; r < 4; ++r) {
                float v = acc[i][j][r] + bj;
                if (RELU) v = fmaxf(v, 0.f);
                const size_t idx = (size_t)(rbase + i * 16 + r) * N + cbase + j * 16;
                if (Cp)  Cp[idx] = v;
                if (Cbf) Cbf[idx] = f2bf(v);
            }
        }
    }
}

// ---------------------------------------------------------------------------
// Deformable sampling + fused softmax, 2-phase LDS-staged.
// R14: R12 structure (64 units/block, 4 lanes/unit, 16B gathers) + PACKED
// meta: one uint per corner = (bf16 weight << 16) | sample_index.
//   weight f32 = as_float(word & 0xffff0000)  (bf16 pattern in high half)
//   byte offset = (word & 0xffff) << 9        (index < 5440, 512B rows)
// Meta 33.8 -> 16.9 KB -> 8 blocks/CU (full 32-wave cap) with the gather
// instruction stream unchanged (R13 showed 8B gathers double VMEM issue).
// ---------------------------------------------------------------------------
__global__ __launch_bounds__(256) void msda_sample(
    const unsigned short* __restrict__ vproj,
    const unsigned short* __restrict__ oa,
    const float* __restrict__ refs,
    unsigned short* __restrict__ outbf)
{
    __shared__ unsigned meta[64][66];   // row stride 264B -> phase2 reads conflict-free

    const int tid = threadIdx.x;
    const int ul  = tid >> 2;
    const int u   = (blockIdx.x << 6) + ul;
    const int h   = u & 7;
    const int bq  = u >> 3;

    // ---------------- phase 1: coords (lane = unit*4 + level)
    {
        const int l   = tid & 3;
        const int sl  = 6 - l;
        const int Nl  = 1 << sl;
        const int msk = Nl - 1;
        const int lsi = (l == 0) ? 0 : (l == 1) ? 4096 : (l == 2) ? 5120 : 5376;

        const size_t oabase = (size_t)bq * 384;
        const short8  offv = *reinterpret_cast<const short8*>(oa + oabase + h * 32 + l * 8);
        const ushort4 lgu  = *reinterpret_cast<const ushort4*>(oa + oabase + 256 + h * 16 + l * 4);
        const float2  rr   = *reinterpret_cast<const float2*>(refs + (size_t)bq * 8 + l * 2);

        float lg0 = bf2f(lgu.x), lg1 = bf2f(lgu.y), lg2 = bf2f(lgu.z), lg3 = bf2f(lgu.w);
        float m = fmaxf(fmaxf(lg0, lg1), fmaxf(lg2, lg3));
        m = fmaxf(m, __shfl_xor(m, 1));
        m = fmaxf(m, __shfl_xor(m, 2));
        float e0 = __expf(lg0 - m), e1 = __expf(lg1 - m),
              e2 = __expf(lg2 - m), e3 = __expf(lg3 - m);
        float s = e0 + e1 + e2 + e3;
        s += __shfl_xor(s, 1);
        s += __shfl_xor(s, 2);
        const float inv = 1.f / s;
        const float aw4[4] = {e0 * inv, e1 * inv, e2 * inv, e3 * inv};

        const float Nf = (float)Nl;
        #pragma unroll
        for (int p = 0; p < 4; ++p) {
            const float ox = bf2fs(offv[p * 2 + 0]);
            const float oy = bf2fs(offv[p * 2 + 1]);
            const float aw = aw4[p];
            const float x = fmaf(rr.x, Nf, ox) - 0.5f;
            const float y = fmaf(rr.y, Nf, oy) - 0.5f;
            const float xf = floorf(x), yf = floorf(y);
            const float tx = x - xf, ty = y - yf;
            const int xi = (int)xf, yi = (int)yf;
            const bool x0v = (unsigned)xi < (unsigned)Nl;
            const bool x1v = (unsigned)(xi + 1) < (unsigned)Nl;
            const bool y0v = (unsigned)yi < (unsigned)Nl;
            const bool y1v = (unsigned)(yi + 1) < (unsigned)Nl;
            const float w0x = (1.f - tx) * aw, w1x = tx * aw;
            const int xm0 = xi & msk, xm1 = (xi + 1) & msk;
            const int ym0 = (yi & msk) << sl, ym1 = ((yi + 1) & msk) << sl;
            const float w00 = (x0v & y0v) ? w0x * (1.f - ty) : 0.f;
            const float w10 = (x1v & y0v) ? w1x * (1.f - ty) : 0.f;
            const float w01 = (x0v & y1v) ? w0x * ty : 0.f;
            const float w11 = (x1v & y1v) ? w1x * ty : 0.f;
            uint2 p01, p23;
            p01.x = ((unsigned)f2bf(w00) << 16) | (unsigned)(lsi + (ym0 | xm0));
            p01.y = ((unsigned)f2bf(w10) << 16) | (unsigned)(lsi + (ym0 | xm1));
            p23.x = ((unsigned)f2bf(w01) << 16) | (unsigned)(lsi + (ym1 | xm0));
            p23.y = ((unsigned)f2bf(w11) << 16) | (unsigned)(lsi + (ym1 | xm1));
            *reinterpret_cast<uint2*>(&meta[ul][l * 16 + p * 4 + 0]) = p01;
            *reinterpret_cast<uint2*>(&meta[ul][l * 16 + p * 4 + 2]) = p23;
        }
    }
    __syncthreads();

    // ---------------- phase 2: gather + MAC (lane = unit*4 + 8-ch chunk)
    const int c = tid & 3;
    const int b = bq / LVTOT;
    const unsigned short* vb = vproj + (size_t)b * (LVTOT * 256) + h * 32 + c * 8;

    float acc[8] = {0.f, 0.f, 0.f, 0.f, 0.f, 0.f, 0.f, 0.f};
    #pragma unroll 4
    for (int j = 0; j < 32; ++j) {
        const uint2 mw = *reinterpret_cast<const uint2*>(&meta[ul][2 * j]);
        const float w0 = __uint_as_float(mw.x & 0xffff0000u);
        const float w1 = __uint_as_float(mw.y & 0xffff0000u);
        const uint4 g0 = *reinterpret_cast<const uint4*>(
            (const char*)vb + ((mw.x & 0xffffu) << 9));
        const uint4 g1 = *reinterpret_cast<const uint4*>(
            (const char*)vb + ((mw.y & 0xffffu) << 9));
        #pragma unroll
        for (int d = 0; d < 4; ++d) {
            const unsigned u0 = (&g0.x)[d];
            acc[2 * d]     = fmaf(w0, __uint_as_float(u0 << 16), acc[2 * d]);
            acc[2 * d + 1] = fmaf(w0, __uint_as_float(u0 & 0xffff0000u), acc[2 * d + 1]);
        }
        #pragma unroll
        for (int d = 0; d < 4; ++d) {
            const unsigned u1 = (&g1.x)[d];
            acc[2 * d]     = fmaf(w1, __uint_as_float(u1 << 16), acc[2 * d]);
            acc[2 * d + 1] = fmaf(w1, __uint_as_float(u1 & 0xffff0000u), acc[2 * d + 1]);
        }
    }

    uint4 ov;
    ov.x = (unsigned)f2bf(acc[0]) | ((unsigned)f2bf(acc[1]) << 16);
    ov.y = (unsigned)f2bf(acc[2]) | ((unsigned)f2bf(acc[3]) << 16);
    ov.z = (unsigned)f2bf(acc[4]) | ((unsigned)f2bf(acc[5]) << 16);
    ov.w = (unsigned)f2bf(acc[6]) | ((unsigned)f2bf(acc[7]) << 16);
    *reinterpret_cast<uint4*>(outbf + (size_t)bq * 256 + h * 32 + c * 8) = ov;
}

// ---------------------------------------------------------------------------
// LayerNorm over 256 with fused adds:
//   x = x1 + (x2?:0); y = LN(x)*g + b; out = (res?:0) + y; optional bf16 copy.
// ---------------------------------------------------------------------------
__global__ __launch_bounds__(256) void ln_fused(
    const float* __restrict__ x1, const float* __restrict__ x2,
    const float* __restrict__ res,
    const float* __restrict__ g, const float* __restrict__ bta,
    float* __restrict__ out, unsigned short* __restrict__ outbf)
{
    const int row  = (blockIdx.x << 2) + (threadIdx.x >> 6);
    const int lane = threadIdx.x & 63;
    const size_t base = (size_t)row * 256 + lane * 4;

    float4 v = *reinterpret_cast<const float4*>(&x1[base]);
    if (x2) {
        float4 u = *reinterpret_cast<const float4*>(&x2[base]);
        v.x += u.x; v.y += u.y; v.z += u.z; v.w += u.w;
    }
    float s1 = v.x + v.y + v.z + v.w;
    float s2 = v.x * v.x + v.y * v.y + v.z * v.z + v.w * v.w;
    #pragma unroll
    for (int s = 1; s < 64; s <<= 1) {
        s1 += __shfl_xor(s1, s);
        s2 += __shfl_xor(s2, s);
    }
    const float mu  = s1 * (1.f / 256.f);
    const float var = s2 * (1.f / 256.f) - mu * mu;
    const float rstd = rsqrtf(var + 1e-5f);

    float4 gg = *reinterpret_cast<const float4*>(&g[lane * 4]);
    float4 bb = *reinterpret_cast<const float4*>(&bta[lane * 4]);
    float4 o;
    o.x = (v.x - mu) * rstd * gg.x + bb.x;
    o.y = (v.y - mu) * rstd * gg.y + bb.y;
    o.z = (v.z - mu) * rstd * gg.z + bb.z;
    o.w = (v.w - mu) * rstd * gg.w + bb.w;
    if (res) {
        float4 r = *reinterpret_cast<const float4*>(&res[base]);
        o.x += r.x; o.y += r.y; o.z += r.z; o.w += r.w;
    }
    *reinterpret_cast<float4*>(&out[base]) = o;
    if (outbf) {
        ushort4 ob;
        ob.x = f2bf(o.x); ob.y = f2bf(o.y); ob.z = f2bf(o.z); ob.w = f2bf(o.w);
        reinterpret_cast<ushort4*>(outbf + base - lane * 4)[lane] = ob;
    }
}

// ---------------------------------------------------------------------------
extern "C" void kernel_launch(void* const* d_in, const int* in_sizes, int n_in,
                              void* d_out, int out_size, void* d_ws, size_t ws_size,
                              hipStream_t stream)
{
    const float* query  = (const float*)d_in[0];
    const float* refs   = (const float*)d_in[1];
    const float* value  = (const float*)d_in[2];
    const float* W_off  = (const float*)d_in[5];
    const float* b_off  = (const float*)d_in[6];
    const float* W_attn = (const float*)d_in[7];
    const float* b_attn = (const float*)d_in[8];
    const float* W_val  = (const float*)d_in[9];
    const float* b_val  = (const float*)d_in[10];
    const float* W_out  = (const float*)d_in[11];
    const float* b_out  = (const float*)d_in[12];
    const float* ln1g   = (const float*)d_in[13];
    const float* ln1b   = (const float*)d_in[14];
    const float* ln2g   = (const float*)d_in[15];
    const float* ln2b   = (const float*)d_in[16];
    const float* W_ff1  = (const float*)d_in[17];
    const float* b_ff1  = (const float*)d_in[18];
    const float* W_ff2  = (const float*)d_in[19];
    const float* b_ff2  = (const float*)d_in[20];
    float* out = (float*)d_out;
    float* ws  = (float*)d_ws;

    const size_t R = (size_t)MROWS * 256;   // 5,570,560 floats
    // Workspace (float offsets), lifetime-reused, total ~4.5R + 1.5MB:
    unsigned short* wt_base = (unsigned short*)ws;         // 753,664 bf16
    float* bias_oa = ws + 376832;                          // 384 (pad to 512)
    const size_t base0 = 377344;
    unsigned short* oa_bf    = (unsigned short*)(ws + base0);              // 0.75R fl
    unsigned short* vproj_bf = (unsigned short*)(ws + base0 + 3 * R / 4);  // 0.5R fl
    unsigned short* msda_bf  = (unsigned short*)(ws + base0 + 5 * R / 4);  // 0.5R fl
    // f1 pad: [base0+1.75R, base0+2R)
    float* tmp  = ws + base0 + 2 * R;                       // R
    float* qbuf = ws + base0 + 3 * R;                       // R
    unsigned short* qbuf_bf = (unsigned short*)(ws + base0 + 4 * R);       // 0.5R fl
    unsigned short* f1_bf = oa_bf;   // spans [base0, base0+2R) over dead regions

    unsigned short* wt_val = wt_base;
    unsigned short* wt_oa  = wt_base + 65536;
    unsigned short* wt_out = wt_base + 163840;
    unsigned short* wt_ff1 = wt_base + 229376;
    unsigned short* wt_ff2 = wt_base + 491520;

    const dim3 blk(256);
    const int mt64 = MROWS / 64;    // 340

    // 0: weight prep
    prep_weights<<<dim3(2946), blk, 0, stream>>>(W_val, W_off, W_attn, W_out,
                                                 W_ff1, W_ff2, b_off, b_attn,
                                                 wt_base, bias_oa);
    // 1: value projection (f32 A), 64x64 tiles -> 1360 blocks
    gemm_rs<1, 64, 64, 1, 0, 1><<<dim3(mt64 * 4), blk, 0, stream>>>(
        value, wt_val, b_val, nullptr, vproj_bf, MROWS, 256, 256);
    // 2: merged offsets+logits projection (f32 A), 64x64 -> 2040 blocks
    gemm_rs<1, 64, 64, 1, 0, 1><<<dim3(mt64 * 6), blk, 0, stream>>>(
        query, wt_oa, bias_oa, nullptr, oa_bf, MROWS, 384, 256);
    // 3: sampling (softmax fused; 64 units/block, packed meta -> 2720 blocks)
    msda_sample<<<dim3(MROWS * 8 / 64), blk, 0, stream>>>(vproj_bf, oa_bf, refs, msda_bf);
    // 4: output projection, 64x64 -> 1360 blocks
    gemm_rs<0, 64, 64, 1, 0, 1><<<dim3(mt64 * 4), blk, 0, stream>>>(
        msda_bf, wt_out, b_out, tmp, nullptr, MROWS, 256, 256);
    // 5: q = value + LN(tmp); bf16 copy for FF1
    ln_fused<<<dim3(MROWS / 4), blk, 0, stream>>>(tmp, nullptr, value,
                                                  ln1g, ln1b, qbuf, qbuf_bf);
    // 6: f1 = relu(q @ W_ff1), 64x64 -> 5440 blocks
    gemm_rs<0, 64, 64, 1, 1, 1><<<dim3(mt64 * 16), blk, 0, stream>>>(
        qbuf_bf, wt_ff1, b_ff1, nullptr, f1_bf, MROWS, 1024, 256);
    // 7: f2 = f1 @ W_ff2, 64x64, K=1024 -> 1360 blocks
    gemm_rs<0, 64, 64, 1, 0, 1><<<dim3(mt64 * 4), blk, 0, stream>>>(
        f1_bf, wt_ff2, b_ff2, tmp, nullptr, MROWS, 256, 1024);
    // 8: out = LN(qbuf + tmp)
    ln_fused<<<dim3(MROWS / 4), blk, 0, stream>>>(qbuf, tmp, nullptr,
                                                  ln2g, ln2b, out, nullptr);
}

// Round 15
// 165.807 us; speedup vs baseline: 1.0536x; 1.0197x over previous
//
#include <hip/hip_runtime.h>
#include <cstddef>

// Problem constants (hard-coded from reference):
// D=256, NH=8, NL=4, NP=4, DH=32, B=4, LV=5440, DFF=1024
// SHAPES = {64,64},{32,32},{16,16},{8,8}; level_start = {0,4096,5120,5376}
#define LVTOT  5440
#define MROWS  (4 * LVTOT)   // 21760 = 128 * 170 = 64 * 340

typedef __attribute__((ext_vector_type(8))) short short8;
typedef __attribute__((ext_vector_type(4))) float floatx4;

static __device__ __forceinline__ unsigned short f2bf(float f) {
    union { float f; unsigned int u; } v; v.f = f;
    unsigned int u = v.u;
    return (unsigned short)((u + 0x7FFFu + ((u >> 16) & 1u)) >> 16);   // RNE
}
static __device__ __forceinline__ float bf2f(unsigned short u) {
    union { unsigned int u; float f; } v; v.u = ((unsigned int)u) << 16; return v.f;
}
static __device__ __forceinline__ float bf2fs(short s) { return bf2f((unsigned short)s); }

// unpack-and-accumulate 8 bf16 channels from a 16B gather with weight w
static __device__ __forceinline__ void macc8(float* acc, float w, const uint4& g) {
    #pragma unroll
    for (int d = 0; d < 4; ++d) {
        const unsigned u = (&g.x)[d];
        acc[2 * d]     = fmaf(w, __uint_as_float(u << 16), acc[2 * d]);
        acc[2 * d + 1] = fmaf(w, __uint_as_float(u & 0xffff0000u), acc[2 * d + 1]);
    }
}

// ---------------------------------------------------------------------------
// One-shot weight prep, all f32 [K][N] -> bf16 [N][K] at fixed slots:
//   val[0,65536) oa[65536,163840) (off rows 0..255 + attn rows 256..383)
//   out[163840,229376) ff1[229376,491520) ff2[491520,753664)
// plus bias_oa[384] floats (b_off ++ b_attn). Grid 2946x256.
// ---------------------------------------------------------------------------
__global__ __launch_bounds__(256) void prep_weights(
    const float* __restrict__ Wv, const float* __restrict__ Wo,
    const float* __restrict__ Wa, const float* __restrict__ Wu,
    const float* __restrict__ W1, const float* __restrict__ W2,
    const float* __restrict__ bo, const float* __restrict__ ba,
    unsigned short* __restrict__ wt, float* __restrict__ bias_oa)
{
    int idx = blockIdx.x * 256 + threadIdx.x;
    if (idx >= 754048) return;
    if (idx >= 753664) {               // bias concat
        int j = idx - 753664;
        bias_oa[j] = (j < 256) ? bo[j] : ba[j - 256];
        return;
    }
    float src;
    if (idx < 65536) {
        int r = idx; src = Wv[(size_t)(r & 255) * 256 + (r >> 8)];
    } else if (idx < 163840) {
        int r = idx - 65536; int n = r >> 8, k = r & 255;
        src = (n < 256) ? Wo[(size_t)k * 256 + n] : Wa[(size_t)k * 128 + (n - 256)];
    } else if (idx < 229376) {
        int r = idx - 163840; src = Wu[(size_t)(r & 255) * 256 + (r >> 8)];
    } else if (idx < 491520) {
        int r = idx - 229376; src = W1[(size_t)(r & 255) * 1024 + (r >> 8)];
    } else {
        int r = idx - 491520; src = W2[(size_t)(r & 1023) * 256 + (r >> 10)];
    }
    wt[idx] = f2bf(src);
}

// ---------------------------------------------------------------------------
// Reg-staged MFMA GEMM, padded LDS (conflict-free), 4 waves (2x2), BK=64.
// 64x64 tiles -> 18.4 KB LDS -> ~8 blocks/CU resident (TLP hides the
// stage->barrier->compute latency chain; proven R12: GEMMs left top-5).
// SWZ=1: XCD-aware bijective remap (m204) + bn-fast tile order -> A-panel
// stays hot in one XCD's L2 (FETCH 44->7.8 MB in R11).
// ---------------------------------------------------------------------------
template<int AF32, int BM, int BN, int SPLITK, int RELU, int SWZ>
__global__ __launch_bounds__(256) void gemm_rs(
    const void* __restrict__ Av, const unsigned short* __restrict__ Bt,
    const float* __restrict__ bias,
    float* __restrict__ C, unsigned short* __restrict__ Cbf,
    int M, int N, int K)
{
    constexpr int AI = BM / 32;
    constexpr int BI = BN / 32;
    constexpr int FM = BM / 32;
    constexpr int FN = BN / 32;

    __shared__ short As[BM][72];
    __shared__ short Bs[BN][72];

    const int tid  = threadIdx.x;
    const int wave = tid >> 6;
    const int lane = tid & 63;
    const int ntiles = N / BN;

    int wgid;
    if (SWZ) {
        const int nwg = gridDim.x;
        const int xcd = blockIdx.x & 7;
        const int t   = blockIdx.x >> 3;
        const int q = nwg >> 3, r = nwg & 7;
        wgid = (xcd < r ? xcd * (q + 1) : r * (q + 1) + (xcd - r) * q) + t;
    } else {
        wgid = blockIdx.x;
    }
    const int tpm = ntiles * SPLITK;
    const int bm  = wgid / tpm;
    const int rem = wgid % tpm;
    const int bn  = rem % ntiles;
    const int ks  = rem / ntiles;

    const int row0 = bm * BM;
    const int col0 = bn * BN;
    const int Kper = K / SPLITK;
    const int kbeg = ks * Kper;

    const int wm = (wave >> 1) * (BM / 2);
    const int wn = (wave & 1) * (BN / 2);

    floatx4 acc[FM][FN];
    #pragma unroll
    for (int i = 0; i < FM; ++i)
        #pragma unroll
        for (int j = 0; j < FN; ++j)
            acc[i][j] = (floatx4){0.f, 0.f, 0.f, 0.f};

    const int lr = tid >> 3;
    const int lc = tid & 7;

    for (int k0 = 0; k0 < Kper; k0 += 64) {
        #pragma unroll
        for (int i = 0; i < AI; ++i) {
            const int r = lr + i * 32;
            if (AF32) {
                const float* Af = (const float*)Av;
                const float4 v0 = *reinterpret_cast<const float4*>(
                    &Af[(size_t)(row0 + r) * K + kbeg + k0 + lc * 8]);
                const float4 v1 = *reinterpret_cast<const float4*>(
                    &Af[(size_t)(row0 + r) * K + kbeg + k0 + lc * 8 + 4]);
                short8 s;
                s[0] = (short)f2bf(v0.x); s[1] = (short)f2bf(v0.y);
                s[2] = (short)f2bf(v0.z); s[3] = (short)f2bf(v0.w);
                s[4] = (short)f2bf(v1.x); s[5] = (short)f2bf(v1.y);
                s[6] = (short)f2bf(v1.z); s[7] = (short)f2bf(v1.w);
                *reinterpret_cast<short8*>(&As[r][lc * 8]) = s;
            } else {
                const unsigned short* Ab = (const unsigned short*)Av;
                *reinterpret_cast<short8*>(&As[r][lc * 8]) =
                    *reinterpret_cast<const short8*>(
                        &Ab[(size_t)(row0 + r) * K + kbeg + k0 + lc * 8]);
            }
        }
        #pragma unroll
        for (int i = 0; i < BI; ++i) {
            const int r = lr + i * 32;
            *reinterpret_cast<short8*>(&Bs[r][lc * 8]) =
                *reinterpret_cast<const short8*>(
                    &Bt[(size_t)(col0 + r) * K + kbeg + k0 + lc * 8]);
        }
        __syncthreads();

        #pragma unroll
        for (int kk = 0; kk < 64; kk += 32) {
            short8 af[FM], bfr[FN];
            #pragma unroll
            for (int i = 0; i < FM; ++i)
                af[i] = *reinterpret_cast<const short8*>(
                    &As[wm + i * 16 + (lane & 15)][kk + (lane >> 4) * 8]);
            #pragma unroll
            for (int j = 0; j < FN; ++j)
                bfr[j] = *reinterpret_cast<const short8*>(
                    &Bs[wn + j * 16 + (lane & 15)][kk + (lane >> 4) * 8]);
            #pragma unroll
            for (int i = 0; i < FM; ++i)
                #pragma unroll
                for (int j = 0; j < FN; ++j)
                    acc[i][j] = __builtin_amdgcn_mfma_f32_16x16x32_bf16(
                        af[i], bfr[j], acc[i][j], 0, 0, 0);
        }
        __syncthreads();
    }

    float* Cp = C ? C + (size_t)ks * M * N : nullptr;
    const int rbase = row0 + wm + (lane >> 4) * 4;
    const int cbase = col0 + wn + (lane & 15);
    #pragma unroll
    for (int j = 0; j < FN; ++j) {
        const float bj = (SPLITK == 1 || ks == 0) ? bias[cbase + j * 16] : 0.f;
        #pragma unroll
        for (int i = 0; i < FM; ++i) {
            #pragma unroll
            for (int r = 0; r < 4; ++r) {
                float v = acc[i][j][r] + bj;
                if (RELU) v = fmaxf(v, 0.f);
                const size_t idx = (size_t)(rbase + i * 16 + r) * N + cbase + j * 16;
                if (Cp)  Cp[idx] = v;
                if (Cbf) Cbf[idx] = f2bf(v);
            }
        }
    }
}

// ---------------------------------------------------------------------------
// Deformable sampling + fused softmax, 2-phase LDS-staged.
// R15: R12 base (64 units/block, 4 lanes/unit, 16B gathers, uint4 meta =
// {off0,w0_f32,off1,w1_f32}) + HAND-PIPELINED phase 2: 16 groups of 4
// corners, 2-deep (load group g+1 while MACing group g) with statically
// named register sets -> >=8 gathers in flight per thread. R12/R13/R14
// showed occupancy doesn't move this kernel; per-thread gather ILP does.
// ---------------------------------------------------------------------------
__global__ __launch_bounds__(256) void msda_sample(
    const unsigned short* __restrict__ vproj,
    const unsigned short* __restrict__ oa,
    const float* __restrict__ refs,
    unsigned short* __restrict__ outbf)
{
    __shared__ uint4 meta[64][33];   // row stride 528B -> 2-way reads (free)

    const int tid = threadIdx.x;
    const int ul  = tid >> 2;
    const int u   = (blockIdx.x << 6) + ul;
    const int h   = u & 7;
    const int bq  = u >> 3;

    // ---------------- phase 1: coords (lane = unit*4 + level)
    {
        const int l   = tid & 3;
        const int sl  = 6 - l;
        const int Nl  = 1 << sl;
        const int msk = Nl - 1;
        const int lsi = (l == 0) ? 0 : (l == 1) ? 4096 : (l == 2) ? 5120 : 5376;

        const size_t oabase = (size_t)bq * 384;
        const short8  offv = *reinterpret_cast<const short8*>(oa + oabase + h * 32 + l * 8);
        const ushort4 lgu  = *reinterpret_cast<const ushort4*>(oa + oabase + 256 + h * 16 + l * 4);
        const float2  rr   = *reinterpret_cast<const float2*>(refs + (size_t)bq * 8 + l * 2);

        float lg0 = bf2f(lgu.x), lg1 = bf2f(lgu.y), lg2 = bf2f(lgu.z), lg3 = bf2f(lgu.w);
        float m = fmaxf(fmaxf(lg0, lg1), fmaxf(lg2, lg3));
        m = fmaxf(m, __shfl_xor(m, 1));
        m = fmaxf(m, __shfl_xor(m, 2));
        float e0 = __expf(lg0 - m), e1 = __expf(lg1 - m),
              e2 = __expf(lg2 - m), e3 = __expf(lg3 - m);
        float s = e0 + e1 + e2 + e3;
        s += __shfl_xor(s, 1);
        s += __shfl_xor(s, 2);
        const float inv = 1.f / s;
        const float aw4[4] = {e0 * inv, e1 * inv, e2 * inv, e3 * inv};

        const float Nf = (float)Nl;
        #pragma unroll
        for (int p = 0; p < 4; ++p) {
            const float ox = bf2fs(offv[p * 2 + 0]);
            const float oy = bf2fs(offv[p * 2 + 1]);
            const float aw = aw4[p];
            const float x = fmaf(rr.x, Nf, ox) - 0.5f;
            const float y = fmaf(rr.y, Nf, oy) - 0.5f;
            const float xf = floorf(x), yf = floorf(y);
            const float tx = x - xf, ty = y - yf;
            const int xi = (int)xf, yi = (int)yf;
            const bool x0v = (unsigned)xi < (unsigned)Nl;
            const bool x1v = (unsigned)(xi + 1) < (unsigned)Nl;
            const bool y0v = (unsigned)yi < (unsigned)Nl;
            const bool y1v = (unsigned)(yi + 1) < (unsigned)Nl;
            const float w0x = (1.f - tx) * aw, w1x = tx * aw;
            const int xm0 = xi & msk, xm1 = (xi + 1) & msk;
            const int ym0 = (yi & msk) << sl, ym1 = ((yi + 1) & msk) << sl;
            uint4 m0, m1;
            m0.x = (unsigned)((lsi + (ym0 | xm0)) << 9);   // byte offset (*512)
            m0.y = __float_as_uint((x0v & y0v) ? w0x * (1.f - ty) : 0.f);
            m0.z = (unsigned)((lsi + (ym0 | xm1)) << 9);
            m0.w = __float_as_uint((x1v & y0v) ? w1x * (1.f - ty) : 0.f);
            m1.x = (unsigned)((lsi + (ym1 | xm0)) << 9);
            m1.y = __float_as_uint((x0v & y1v) ? w0x * ty : 0.f);
            m1.z = (unsigned)((lsi + (ym1 | xm1)) << 9);
            m1.w = __float_as_uint((x1v & y1v) ? w1x * ty : 0.f);
            meta[ul][l * 8 + p * 2 + 0] = m0;
            meta[ul][l * 8 + p * 2 + 1] = m1;
        }
    }
    __syncthreads();

    // ---------------- phase 2: gather + MAC, 2-deep pipelined
    const int c = tid & 3;
    const int b = bq / LVTOT;
    const char* vb = (const char*)(vproj + (size_t)b * (LVTOT * 256) + h * 32 + c * 8);
    const uint4* mrow = &meta[ul][0];

    float acc[8] = {0.f, 0.f, 0.f, 0.f, 0.f, 0.f, 0.f, 0.f};

    // group = 2 meta-slots = 4 corners; 16 groups total
    uint4 mA0, mA1, gA0, gA1, gA2, gA3;
    uint4 mB0, mB1, gB0, gB1, gB2, gB3;

#define LOADG(m0, m1, g0, g1, g2, g3, grp)                                   \
    m0 = mrow[(grp) * 2]; m1 = mrow[(grp) * 2 + 1];                          \
    g0 = *reinterpret_cast<const uint4*>(vb + m0.x);                         \
    g1 = *reinterpret_cast<const uint4*>(vb + m0.z);                         \
    g2 = *reinterpret_cast<const uint4*>(vb + m1.x);                         \
    g3 = *reinterpret_cast<const uint4*>(vb + m1.z);

#define MACG(m0, m1, g0, g1, g2, g3)                                         \
    macc8(acc, __uint_as_float(m0.y), g0);                                   \
    macc8(acc, __uint_as_float(m0.w), g1);                                   \
    macc8(acc, __uint_as_float(m1.y), g2);                                   \
    macc8(acc, __uint_as_float(m1.w), g3);

    LOADG(mA0, mA1, gA0, gA1, gA2, gA3, 0)
    LOADG(mB0, mB1, gB0, gB1, gB2, gB3, 1)
    #pragma unroll
    for (int grp = 0; grp < 16; grp += 2) {
        MACG(mA0, mA1, gA0, gA1, gA2, gA3)
        if (grp + 2 < 16) { LOADG(mA0, mA1, gA0, gA1, gA2, gA3, grp + 2) }
        MACG(mB0, mB1, gB0, gB1, gB2, gB3)
        if (grp + 3 < 16) { LOADG(mB0, mB1, gB0, gB1, gB2, gB3, grp + 3) }
    }
#undef LOADG
#undef MACG

    uint4 ov;
    ov.x = (unsigned)f2bf(acc[0]) | ((unsigned)f2bf(acc[1]) << 16);
    ov.y = (unsigned)f2bf(acc[2]) | ((unsigned)f2bf(acc[3]) << 16);
    ov.z = (unsigned)f2bf(acc[4]) | ((unsigned)f2bf(acc[5]) << 16);
    ov.w = (unsigned)f2bf(acc[6]) | ((unsigned)f2bf(acc[7]) << 16);
    *reinterpret_cast<uint4*>(outbf + (size_t)bq * 256 + h * 32 + c * 8) = ov;
}

// ---------------------------------------------------------------------------
// LayerNorm over 256 with fused adds:
//   x = x1 + (x2?:0); y = LN(x)*g + b; out = (res?:0) + y; optional bf16 copy.
// ---------------------------------------------------------------------------
__global__ __launch_bounds__(256) void ln_fused(
    const float* __restrict__ x1, const float* __restrict__ x2,
    const float* __restrict__ res,
    const float* __restrict__ g, const float* __restrict__ bta,
    float* __restrict__ out, unsigned short* __restrict__ outbf)
{
    const int row  = (blockIdx.x << 2) + (threadIdx.x >> 6);
    const int lane = threadIdx.x & 63;
    const size_t base = (size_t)row * 256 + lane * 4;

    float4 v = *reinterpret_cast<const float4*>(&x1[base]);
    if (x2) {
        float4 u = *reinterpret_cast<const float4*>(&x2[base]);
        v.x += u.x; v.y += u.y; v.z += u.z; v.w += u.w;
    }
    float s1 = v.x + v.y + v.z + v.w;
    float s2 = v.x * v.x + v.y * v.y + v.z * v.z + v.w * v.w;
    #pragma unroll
    for (int s = 1; s < 64; s <<= 1) {
        s1 += __shfl_xor(s1, s);
        s2 += __shfl_xor(s2, s);
    }
    const float mu  = s1 * (1.f / 256.f);
    const float var = s2 * (1.f / 256.f) - mu * mu;
    const float rstd = rsqrtf(var + 1e-5f);

    float4 gg = *reinterpret_cast<const float4*>(&g[lane * 4]);
    float4 bb = *reinterpret_cast<const float4*>(&bta[lane * 4]);
    float4 o;
    o.x = (v.x - mu) * rstd * gg.x + bb.x;
    o.y = (v.y - mu) * rstd * gg.y + bb.y;
    o.z = (v.z - mu) * rstd * gg.z + bb.z;
    o.w = (v.w - mu) * rstd * gg.w + bb.w;
    if (res) {
        float4 r = *reinterpret_cast<const float4*>(&res[base]);
        o.x += r.x; o.y += r.y; o.z += r.z; o.w += r.w;
    }
    *reinterpret_cast<float4*>(&out[base]) = o;
    if (outbf) {
        ushort4 ob;
        ob.x = f2bf(o.x); ob.y = f2bf(o.y); ob.z = f2bf(o.z); ob.w = f2bf(o.w);
        reinterpret_cast<ushort4*>(outbf + base - lane * 4)[lane] = ob;
    }
}

// ---------------------------------------------------------------------------
extern "C" void kernel_launch(void* const* d_in, const int* in_sizes, int n_in,
                              void* d_out, int out_size, void* d_ws, size_t ws_size,
                              hipStream_t stream)
{
    const float* query  = (const float*)d_in[0];
    const float* refs   = (const float*)d_in[1];
    const float* value  = (const float*)d_in[2];
    const float* W_off  = (const float*)d_in[5];
    const float* b_off  = (const float*)d_in[6];
    const float* W_attn = (const float*)d_in[7];
    const float* b_attn = (const float*)d_in[8];
    const float* W_val  = (const float*)d_in[9];
    const float* b_val  = (const float*)d_in[10];
    const float* W_out  = (const float*)d_in[11];
    const float* b_out  = (const float*)d_in[12];
    const float* ln1g   = (const float*)d_in[13];
    const float* ln1b   = (const float*)d_in[14];
    const float* ln2g   = (const float*)d_in[15];
    const float* ln2b   = (const float*)d_in[16];
    const float* W_ff1  = (const float*)d_in[17];
    const float* b_ff1  = (const float*)d_in[18];
    const float* W_ff2  = (const float*)d_in[19];
    const float* b_ff2  = (const float*)d_in[20];
    float* out = (float*)d_out;
    float* ws  = (float*)d_ws;

    const size_t R = (size_t)MROWS * 256;   // 5,570,560 floats
    // Workspace (float offsets), lifetime-reused, total ~4.5R + 1.5MB:
    unsigned short* wt_base = (unsigned short*)ws;         // 753,664 bf16
    float* bias_oa = ws + 376832;                          // 384 (pad to 512)
    const size_t base0 = 377344;
    unsigned short* oa_bf    = (unsigned short*)(ws + base0);              // 0.75R fl
    unsigned short* vproj_bf = (unsigned short*)(ws + base0 + 3 * R / 4);  // 0.5R fl
    unsigned short* msda_bf  = (unsigned short*)(ws + base0 + 5 * R / 4);  // 0.5R fl
    // f1 pad: [base0+1.75R, base0+2R)
    float* tmp  = ws + base0 + 2 * R;                       // R
    float* qbuf = ws + base0 + 3 * R;                       // R
    unsigned short* qbuf_bf = (unsigned short*)(ws + base0 + 4 * R);       // 0.5R fl
    unsigned short* f1_bf = oa_bf;   // spans [base0, base0+2R) over dead regions

    unsigned short* wt_val = wt_base;
    unsigned short* wt_oa  = wt_base + 65536;
    unsigned short* wt_out = wt_base + 163840;
    unsigned short* wt_ff1 = wt_base + 229376;
    unsigned short* wt_ff2 = wt_base + 491520;

    const dim3 blk(256);
    const int mt64 = MROWS / 64;    // 340

    // 0: weight prep
    prep_weights<<<dim3(2946), blk, 0, stream>>>(W_val, W_off, W_attn, W_out,
                                                 W_ff1, W_ff2, b_off, b_attn,
                                                 wt_base, bias_oa);
    // 1: value projection (f32 A), 64x64 tiles -> 1360 blocks
    gemm_rs<1, 64, 64, 1, 0, 1><<<dim3(mt64 * 4), blk, 0, stream>>>(
        value, wt_val, b_val, nullptr, vproj_bf, MROWS, 256, 256);
    // 2: merged offsets+logits projection (f32 A), 64x64 -> 2040 blocks
    gemm_rs<1, 64, 64, 1, 0, 1><<<dim3(mt64 * 6), blk, 0, stream>>>(
        query, wt_oa, bias_oa, nullptr, oa_bf, MROWS, 384, 256);
    // 3: sampling (softmax fused; 64 units/block, pipelined -> 2720 blocks)
    msda_sample<<<dim3(MROWS * 8 / 64), blk, 0, stream>>>(vproj_bf, oa_bf, refs, msda_bf);
    // 4: output projection, 64x64 -> 1360 blocks
    gemm_rs<0, 64, 64, 1, 0, 1><<<dim3(mt64 * 4), blk, 0, stream>>>(
        msda_bf, wt_out, b_out, tmp, nullptr, MROWS, 256, 256);
    // 5: q = value + LN(tmp); bf16 copy for FF1
    ln_fused<<<dim3(MROWS / 4), blk, 0, stream>>>(tmp, nullptr, value,
                                                  ln1g, ln1b, qbuf, qbuf_bf);
    // 6: f1 = relu(q @ W_ff1), 64x64 -> 5440 blocks
    gemm_rs<0, 64, 64, 1, 1, 1><<<dim3(mt64 * 16), blk, 0, stream>>>(
        qbuf_bf, wt_ff1, b_ff1, nullptr, f1_bf, MROWS, 1024, 256);
    // 7: f2 = f1 @ W_ff2, 64x64, K=1024 -> 1360 blocks
    gemm_rs<0, 64, 64, 1, 0, 1><<<dim3(mt64 * 4), blk, 0, stream>>>(
        f1_bf, wt_ff2, b_ff2, tmp, nullptr, MROWS, 256, 1024);
    // 8: out = LN(qbuf + tmp)
    ln_fused<<<dim3(MROWS / 4), blk, 0, stream>>>(qbuf, tmp, nullptr,
                                                  ln2g, ln2b, out, nullptr);
}

// Round 16
// 162.425 us; speedup vs baseline: 1.0755x; 1.0208x over previous
//
#include <hip/hip_runtime.h>
#include <cstddef>

// Problem constants (hard-coded from reference):
// D=256, NH=8, NL=4, NP=4, DH=32, B=4, LV=5440, DFF=1024
// SHAPES = {64,64},{32,32},{16,16},{8,8}; level_start = {0,4096,5120,5376}
#define LVTOT  5440
#define MROWS  (4 * LVTOT)   // 21760 = 128 * 170 = 64 * 340

typedef __attribute__((ext_vector_type(8))) short short8;
typedef __attribute__((ext_vector_type(4))) float floatx4;

static __device__ __forceinline__ unsigned short f2bf(float f) {
    union { float f; unsigned int u; } v; v.f = f;
    unsigned int u = v.u;
    return (unsigned short)((u + 0x7FFFu + ((u >> 16) & 1u)) >> 16);   // RNE
}
static __device__ __forceinline__ float bf2f(unsigned short u) {
    union { unsigned int u; float f; } v; v.u = ((unsigned int)u) << 16; return v.f;
}
static __device__ __forceinline__ float bf2fs(short s) { return bf2f((unsigned short)s); }

// ---------------------------------------------------------------------------
// One-shot weight prep, all f32 [K][N] -> bf16 [N][K] at fixed slots:
//   val[0,65536) oa[65536,163840) (off rows 0..255 + attn rows 256..383)
//   out[163840,229376) ff1[229376,491520) ff2[491520,753664)
// plus bias_oa[384] floats (b_off ++ b_attn). Grid 2946x256.
// ---------------------------------------------------------------------------
__global__ __launch_bounds__(256) void prep_weights(
    const float* __restrict__ Wv, const float* __restrict__ Wo,
    const float* __restrict__ Wa, const float* __restrict__ Wu,
    const float* __restrict__ W1, const float* __restrict__ W2,
    const float* __restrict__ bo, const float* __restrict__ ba,
    unsigned short* __restrict__ wt, float* __restrict__ bias_oa)
{
    int idx = blockIdx.x * 256 + threadIdx.x;
    if (idx >= 754048) return;
    if (idx >= 753664) {               // bias concat
        int j = idx - 753664;
        bias_oa[j] = (j < 256) ? bo[j] : ba[j - 256];
        return;
    }
    float src;
    if (idx < 65536) {
        int r = idx; src = Wv[(size_t)(r & 255) * 256 + (r >> 8)];
    } else if (idx < 163840) {
        int r = idx - 65536; int n = r >> 8, k = r & 255;
        src = (n < 256) ? Wo[(size_t)k * 256 + n] : Wa[(size_t)k * 128 + (n - 256)];
    } else if (idx < 229376) {
        int r = idx - 163840; src = Wu[(size_t)(r & 255) * 256 + (r >> 8)];
    } else if (idx < 491520) {
        int r = idx - 229376; src = W1[(size_t)(r & 255) * 1024 + (r >> 8)];
    } else {
        int r = idx - 491520; src = W2[(size_t)(r & 1023) * 256 + (r >> 10)];
    }
    wt[idx] = f2bf(src);
}

// ---------------------------------------------------------------------------
// Reg-staged MFMA GEMM, padded LDS (conflict-free), 4 waves (2x2), BK=64.
// 64x64 tiles -> 18.4 KB LDS -> ~8 blocks/CU resident (TLP hides the
// stage->barrier->compute latency chain; proven R12: GEMMs left top-5).
// SWZ=1: XCD-aware bijective remap (m204) + bn-fast tile order -> A-panel
// stays hot in one XCD's L2 (FETCH 44->7.8 MB in R11).
// ---------------------------------------------------------------------------
template<int AF32, int BM, int BN, int SPLITK, int RELU, int SWZ>
__global__ __launch_bounds__(256) void gemm_rs(
    const void* __restrict__ Av, const unsigned short* __restrict__ Bt,
    const float* __restrict__ bias,
    float* __restrict__ C, unsigned short* __restrict__ Cbf,
    int M, int N, int K)
{
    constexpr int AI = BM / 32;
    constexpr int BI = BN / 32;
    constexpr int FM = BM / 32;
    constexpr int FN = BN / 32;

    __shared__ short As[BM][72];
    __shared__ short Bs[BN][72];

    const int tid  = threadIdx.x;
    const int wave = tid >> 6;
    const int lane = tid & 63;
    const int ntiles = N / BN;

    int wgid;
    if (SWZ) {
        const int nwg = gridDim.x;
        const int xcd = blockIdx.x & 7;
        const int t   = blockIdx.x >> 3;
        const int q = nwg >> 3, r = nwg & 7;
        wgid = (xcd < r ? xcd * (q + 1) : r * (q + 1) + (xcd - r) * q) + t;
    } else {
        wgid = blockIdx.x;
    }
    const int tpm = ntiles * SPLITK;
    const int bm  = wgid / tpm;
    const int rem = wgid % tpm;
    const int bn  = rem % ntiles;
    const int ks  = rem / ntiles;

    const int row0 = bm * BM;
    const int col0 = bn * BN;
    const int Kper = K / SPLITK;
    const int kbeg = ks * Kper;

    const int wm = (wave >> 1) * (BM / 2);
    const int wn = (wave & 1) * (BN / 2);

    floatx4 acc[FM][FN];
    #pragma unroll
    for (int i = 0; i < FM; ++i)
        #pragma unroll
        for (int j = 0; j < FN; ++j)
            acc[i][j] = (floatx4){0.f, 0.f, 0.f, 0.f};

    const int lr = tid >> 3;
    const int lc = tid & 7;

    for (int k0 = 0; k0 < Kper; k0 += 64) {
        #pragma unroll
        for (int i = 0; i < AI; ++i) {
            const int r = lr + i * 32;
            if (AF32) {
                const float* Af = (const float*)Av;
                const float4 v0 = *reinterpret_cast<const float4*>(
                    &Af[(size_t)(row0 + r) * K + kbeg + k0 + lc * 8]);
                const float4 v1 = *reinterpret_cast<const float4*>(
                    &Af[(size_t)(row0 + r) * K + kbeg + k0 + lc * 8 + 4]);
                short8 s;
                s[0] = (short)f2bf(v0.x); s[1] = (short)f2bf(v0.y);
                s[2] = (short)f2bf(v0.z); s[3] = (short)f2bf(v0.w);
                s[4] = (short)f2bf(v1.x); s[5] = (short)f2bf(v1.y);
                s[6] = (short)f2bf(v1.z); s[7] = (short)f2bf(v1.w);
                *reinterpret_cast<short8*>(&As[r][lc * 8]) = s;
            } else {
                const unsigned short* Ab = (const unsigned short*)Av;
                *reinterpret_cast<short8*>(&As[r][lc * 8]) =
                    *reinterpret_cast<const short8*>(
                        &Ab[(size_t)(row0 + r) * K + kbeg + k0 + lc * 8]);
            }
        }
        #pragma unroll
        for (int i = 0; i < BI; ++i) {
            const int r = lr + i * 32;
            *reinterpret_cast<short8*>(&Bs[r][lc * 8]) =
                *reinterpret_cast<const short8*>(
                    &Bt[(size_t)(col0 + r) * K + kbeg + k0 + lc * 8]);
        }
        __syncthreads();

        #pragma unroll
        for (int kk = 0; kk < 64; kk += 32) {
            short8 af[FM], bfr[FN];
            #pragma unroll
            for (int i = 0; i < FM; ++i)
                af[i] = *reinterpret_cast<const short8*>(
                    &As[wm + i * 16 + (lane & 15)][kk + (lane >> 4) * 8]);
            #pragma unroll
            for (int j = 0; j < FN; ++j)
                bfr[j] = *reinterpret_cast<const short8*>(
                    &Bs[wn + j * 16 + (lane & 15)][kk + (lane >> 4) * 8]);
            #pragma unroll
            for (int i = 0; i < FM; ++i)
                #pragma unroll
                for (int j = 0; j < FN; ++j)
                    acc[i][j] = __builtin_amdgcn_mfma_f32_16x16x32_bf16(
                        af[i], bfr[j], acc[i][j], 0, 0, 0);
        }
        __syncthreads();
    }

    float* Cp = C ? C + (size_t)ks * M * N : nullptr;
    const int rbase = row0 + wm + (lane >> 4) * 4;
    const int cbase = col0 + wn + (lane & 15);
    #pragma unroll
    for (int j = 0; j < FN; ++j) {
        const float bj = (SPLITK == 1 || ks == 0) ? bias[cbase + j * 16] : 0.f;
        #pragma unroll
        for (int i = 0; i < FM; ++i) {
            #pragma unroll
            for (int r = 0; r < 4; ++r) {
                float v = acc[i][j][r] + bj;
                if (RELU) v = fmaxf(v, 0.f);
                const size_t idx = (size_t)(rbase + i * 16 + r) * N + cbase + j * 16;
                if (Cp)  Cp[idx] = v;
                if (Cbf) Cbf[idx] = f2bf(v);
            }
        }
    }
}

// ---------------------------------------------------------------------------
// Deformable sampling + fused softmax, 2-phase LDS-staged.
// EXACT R12 structure (measured 41 us): 64 units/block, 4 lanes/unit,
// 16B gathers (1 cache line per unit-corner), uint4 meta {off0,w0,off1,w1},
// compiler-scheduled unroll-4 MAC loop. R13-R15 variants (occupancy up,
// width down, hand pipeline) all regressed — this is the measured optimum.
// ---------------------------------------------------------------------------
__global__ __launch_bounds__(256) void msda_sample(
    const unsigned short* __restrict__ vproj,
    const unsigned short* __restrict__ oa,
    const float* __restrict__ refs,
    unsigned short* __restrict__ outbf)
{
    __shared__ uint4 meta[64][33];

    const int tid = threadIdx.x;
    const int ul  = tid >> 2;
    const int u   = (blockIdx.x << 6) + ul;
    const int h   = u & 7;
    const int bq  = u >> 3;

    {
        const int l   = tid & 3;
        const int sl  = 6 - l;
        const int Nl  = 1 << sl;
        const int msk = Nl - 1;
        const int lsi = (l == 0) ? 0 : (l == 1) ? 4096 : (l == 2) ? 5120 : 5376;

        const size_t oabase = (size_t)bq * 384;
        const short8  offv = *reinterpret_cast<const short8*>(oa + oabase + h * 32 + l * 8);
        const ushort4 lgu  = *reinterpret_cast<const ushort4*>(oa + oabase + 256 + h * 16 + l * 4);
        const float2  rr   = *reinterpret_cast<const float2*>(refs + (size_t)bq * 8 + l * 2);

        float lg0 = bf2f(lgu.x), lg1 = bf2f(lgu.y), lg2 = bf2f(lgu.z), lg3 = bf2f(lgu.w);
        float m = fmaxf(fmaxf(lg0, lg1), fmaxf(lg2, lg3));
        m = fmaxf(m, __shfl_xor(m, 1));
        m = fmaxf(m, __shfl_xor(m, 2));
        float e0 = __expf(lg0 - m), e1 = __expf(lg1 - m),
              e2 = __expf(lg2 - m), e3 = __expf(lg3 - m);
        float s = e0 + e1 + e2 + e3;
        s += __shfl_xor(s, 1);
        s += __shfl_xor(s, 2);
        const float inv = 1.f / s;
        const float aw4[4] = {e0 * inv, e1 * inv, e2 * inv, e3 * inv};

        const float Nf = (float)Nl;
        #pragma unroll
        for (int p = 0; p < 4; ++p) {
            const float ox = bf2fs(offv[p * 2 + 0]);
            const float oy = bf2fs(offv[p * 2 + 1]);
            const float aw = aw4[p];
            const float x = fmaf(rr.x, Nf, ox) - 0.5f;
            const float y = fmaf(rr.y, Nf, oy) - 0.5f;
            const float xf = floorf(x), yf = floorf(y);
            const float tx = x - xf, ty = y - yf;
            const int xi = (int)xf, yi = (int)yf;
            const bool x0v = (unsigned)xi < (unsigned)Nl;
            const bool x1v = (unsigned)(xi + 1) < (unsigned)Nl;
            const bool y0v = (unsigned)yi < (unsigned)Nl;
            const bool y1v = (unsigned)(yi + 1) < (unsigned)Nl;
            const float w0x = (1.f - tx) * aw, w1x = tx * aw;
            const int xm0 = xi & msk, xm1 = (xi + 1) & msk;
            const int ym0 = (yi & msk) << sl, ym1 = ((yi + 1) & msk) << sl;
            uint4 m0, m1;
            m0.x = (unsigned)((lsi + (ym0 | xm0)) << 9);
            m0.y = __float_as_uint((x0v & y0v) ? w0x * (1.f - ty) : 0.f);
            m0.z = (unsigned)((lsi + (ym0 | xm1)) << 9);
            m0.w = __float_as_uint((x1v & y0v) ? w1x * (1.f - ty) : 0.f);
            m1.x = (unsigned)((lsi + (ym1 | xm0)) << 9);
            m1.y = __float_as_uint((x0v & y1v) ? w0x * ty : 0.f);
            m1.z = (unsigned)((lsi + (ym1 | xm1)) << 9);
            m1.w = __float_as_uint((x1v & y1v) ? w1x * ty : 0.f);
            meta[ul][l * 8 + p * 2 + 0] = m0;
            meta[ul][l * 8 + p * 2 + 1] = m1;
        }
    }
    __syncthreads();

    const int c = tid & 3;
    const int b = bq / LVTOT;
    const unsigned short* vb = vproj + (size_t)b * (LVTOT * 256) + h * 32 + c * 8;

    float acc[8] = {0.f, 0.f, 0.f, 0.f, 0.f, 0.f, 0.f, 0.f};
    #pragma unroll 4
    for (int j = 0; j < 32; ++j) {
        const uint4 mt = meta[ul][j];
        const uint4 g0 = *reinterpret_cast<const uint4*>((const char*)vb + mt.x);
        const uint4 g1 = *reinterpret_cast<const uint4*>((const char*)vb + mt.z);
        const float w0 = __uint_as_float(mt.y);
        const float w1 = __uint_as_float(mt.w);
        #pragma unroll
        for (int d = 0; d < 4; ++d) {
            const unsigned u0 = (&g0.x)[d];
            acc[2 * d]     = fmaf(w0, __uint_as_float(u0 << 16), acc[2 * d]);
            acc[2 * d + 1] = fmaf(w0, __uint_as_float(u0 & 0xffff0000u), acc[2 * d + 1]);
        }
        #pragma unroll
        for (int d = 0; d < 4; ++d) {
            const unsigned u1 = (&g1.x)[d];
            acc[2 * d]     = fmaf(w1, __uint_as_float(u1 << 16), acc[2 * d]);
            acc[2 * d + 1] = fmaf(w1, __uint_as_float(u1 & 0xffff0000u), acc[2 * d + 1]);
        }
    }

    uint4 ov;
    ov.x = (unsigned)f2bf(acc[0]) | ((unsigned)f2bf(acc[1]) << 16);
    ov.y = (unsigned)f2bf(acc[2]) | ((unsigned)f2bf(acc[3]) << 16);
    ov.z = (unsigned)f2bf(acc[4]) | ((unsigned)f2bf(acc[5]) << 16);
    ov.w = (unsigned)f2bf(acc[6]) | ((unsigned)f2bf(acc[7]) << 16);
    *reinterpret_cast<uint4*>(outbf + (size_t)bq * 256 + h * 32 + c * 8) = ov;
}

// ---------------------------------------------------------------------------
// LayerNorm over 256 with fused adds:
//   x = (x1?:0) + (xbf?:0);  y = LN(x)*g + b;  out = (res?:0) + y;
//   optional bf16 copy. xbf is a bf16 input port (halves LN input traffic
//   for GEMM-produced operands).
// ---------------------------------------------------------------------------
__global__ __launch_bounds__(256) void ln_fused(
    const float* __restrict__ x1, const unsigned short* __restrict__ xbf,
    const float* __restrict__ res,
    const float* __restrict__ g, const float* __restrict__ bta,
    float* __restrict__ out, unsigned short* __restrict__ outbf)
{
    const int row  = (blockIdx.x << 2) + (threadIdx.x >> 6);
    const int lane = threadIdx.x & 63;
    const size_t base = (size_t)row * 256 + lane * 4;

    float4 v = {0.f, 0.f, 0.f, 0.f};
    if (x1) {
        float4 u = *reinterpret_cast<const float4*>(&x1[base]);
        v.x += u.x; v.y += u.y; v.z += u.z; v.w += u.w;
    }
    if (xbf) {
        ushort4 ub = *reinterpret_cast<const ushort4*>(&xbf[base]);
        v.x += bf2f(ub.x); v.y += bf2f(ub.y); v.z += bf2f(ub.z); v.w += bf2f(ub.w);
    }
    float s1 = v.x + v.y + v.z + v.w;
    float s2 = v.x * v.x + v.y * v.y + v.z * v.z + v.w * v.w;
    #pragma unroll
    for (int s = 1; s < 64; s <<= 1) {
        s1 += __shfl_xor(s1, s);
        s2 += __shfl_xor(s2, s);
    }
    const float mu  = s1 * (1.f / 256.f);
    const float var = s2 * (1.f / 256.f) - mu * mu;
    const float rstd = rsqrtf(var + 1e-5f);

    float4 gg = *reinterpret_cast<const float4*>(&g[lane * 4]);
    float4 bb = *reinterpret_cast<const float4*>(&bta[lane * 4]);
    float4 o;
    o.x = (v.x - mu) * rstd * gg.x + bb.x;
    o.y = (v.y - mu) * rstd * gg.y + bb.y;
    o.z = (v.z - mu) * rstd * gg.z + bb.z;
    o.w = (v.w - mu) * rstd * gg.w + bb.w;
    if (res) {
        float4 r = *reinterpret_cast<const float4*>(&res[base]);
        o.x += r.x; o.y += r.y; o.z += r.z; o.w += r.w;
    }
    *reinterpret_cast<float4*>(&out[base]) = o;
    if (outbf) {
        ushort4 ob;
        ob.x = f2bf(o.x); ob.y = f2bf(o.y); ob.z = f2bf(o.z); ob.w = f2bf(o.w);
        reinterpret_cast<ushort4*>(outbf + base - lane * 4)[lane] = ob;
    }
}

// ---------------------------------------------------------------------------
extern "C" void kernel_launch(void* const* d_in, const int* in_sizes, int n_in,
                              void* d_out, int out_size, void* d_ws, size_t ws_size,
                              hipStream_t stream)
{
    const float* query  = (const float*)d_in[0];
    const float* refs   = (const float*)d_in[1];
    const float* value  = (const float*)d_in[2];
    const float* W_off  = (const float*)d_in[5];
    const float* b_off  = (const float*)d_in[6];
    const float* W_attn = (const float*)d_in[7];
    const float* b_attn = (const float*)d_in[8];
    const float* W_val  = (const float*)d_in[9];
    const float* b_val  = (const float*)d_in[10];
    const float* W_out  = (const float*)d_in[11];
    const float* b_out  = (const float*)d_in[12];
    const float* ln1g   = (const float*)d_in[13];
    const float* ln1b   = (const float*)d_in[14];
    const float* ln2g   = (const float*)d_in[15];
    const float* ln2b   = (const float*)d_in[16];
    const float* W_ff1  = (const float*)d_in[17];
    const float* b_ff1  = (const float*)d_in[18];
    const float* W_ff2  = (const float*)d_in[19];
    const float* b_ff2  = (const float*)d_in[20];
    float* out = (float*)d_out;
    float* ws  = (float*)d_ws;

    const size_t R = (size_t)MROWS * 256;   // 5,570,560 floats
    // Workspace (float offsets), lifetime-reused:
    unsigned short* wt_base = (unsigned short*)ws;         // 753,664 bf16
    float* bias_oa = ws + 376832;                          // 384 (pad to 512)
    const size_t base0 = 377344;
    unsigned short* oa_bf    = (unsigned short*)(ws + base0);              // 0.75R fl
    unsigned short* vproj_bf = (unsigned short*)(ws + base0 + 3 * R / 4);  // 0.5R fl
    unsigned short* msda_bf  = (unsigned short*)(ws + base0 + 5 * R / 4);  // 0.5R fl
    // f1 pad: [base0+1.75R, base0+2R)
    unsigned short* tmp_bf = (unsigned short*)(ws + base0 + 2 * R);        // 0.5R fl
    float* qbuf = ws + base0 + 3 * R;                       // R
    unsigned short* qbuf_bf = (unsigned short*)(ws + base0 + 4 * R);       // 0.5R fl
    unsigned short* f1_bf = oa_bf;   // spans [base0, base0+2R) over dead regions

    unsigned short* wt_val = wt_base;
    unsigned short* wt_oa  = wt_base + 65536;
    unsigned short* wt_out = wt_base + 163840;
    unsigned short* wt_ff1 = wt_base + 229376;
    unsigned short* wt_ff2 = wt_base + 491520;

    const dim3 blk(256);
    const int mt64 = MROWS / 64;    // 340

    // 0: weight prep
    prep_weights<<<dim3(2946), blk, 0, stream>>>(W_val, W_off, W_attn, W_out,
                                                 W_ff1, W_ff2, b_off, b_attn,
                                                 wt_base, bias_oa);
    // 1: value projection (f32 A), 64x64 tiles -> 1360 blocks
    gemm_rs<1, 64, 64, 1, 0, 1><<<dim3(mt64 * 4), blk, 0, stream>>>(
        value, wt_val, b_val, nullptr, vproj_bf, MROWS, 256, 256);
    // 2: merged offsets+logits projection (f32 A), 64x64 -> 2040 blocks
    gemm_rs<1, 64, 64, 1, 0, 1><<<dim3(mt64 * 6), blk, 0, stream>>>(
        query, wt_oa, bias_oa, nullptr, oa_bf, MROWS, 384, 256);
    // 3: sampling (R12 config, 64 units/block -> 2720 blocks)
    msda_sample<<<dim3(MROWS * 8 / 64), blk, 0, stream>>>(vproj_bf, oa_bf, refs, msda_bf);
    // 4: output projection, 64x64 -> 1360 blocks, bf16 out
    gemm_rs<0, 64, 64, 1, 0, 1><<<dim3(mt64 * 4), blk, 0, stream>>>(
        msda_bf, wt_out, b_out, nullptr, tmp_bf, MROWS, 256, 256);
    // 5: q = value + LN(tmp_bf); f32 + bf16 copies
    ln_fused<<<dim3(MROWS / 4), blk, 0, stream>>>(nullptr, tmp_bf, value,
                                                  ln1g, ln1b, qbuf, qbuf_bf);
    // 6: f1 = relu(q @ W_ff1), 64x64 -> 5440 blocks
    gemm_rs<0, 64, 64, 1, 1, 1><<<dim3(mt64 * 16), blk, 0, stream>>>(
        qbuf_bf, wt_ff1, b_ff1, nullptr, f1_bf, MROWS, 1024, 256);
    // 7: f2 = f1 @ W_ff2, 64x64, K=1024 -> 1360 blocks, bf16 out
    gemm_rs<0, 64, 64, 1, 0, 1><<<dim3(mt64 * 4), blk, 0, stream>>>(
        f1_bf, wt_ff2, b_ff2, nullptr, tmp_bf, MROWS, 256, 1024);
    // 8: out = LN(qbuf + tmp_bf)
    ln_fused<<<dim3(MROWS / 4), blk, 0, stream>>>(qbuf, tmp_bf, nullptr,
                                                  ln2g, ln2b, out, nullptr);
}

// Round 17
// 154.455 us; speedup vs baseline: 1.1310x; 1.0516x over previous
//
#include <hip/hip_runtime.h>
#include <cstddef>

// Problem constants (hard-coded from reference):
// D=256, NH=8, NL=4, NP=4, DH=32, B=4, LV=5440, DFF=1024
// SHAPES = {64,64},{32,32},{16,16},{8,8}; level_start = {0,4096,5120,5376}
#define LVTOT  5440
#define MROWS  (4 * LVTOT)   // 21760 = 128 * 170 = 64 * 340 = 32 * 680

typedef __attribute__((ext_vector_type(8))) short short8;
typedef __attribute__((ext_vector_type(4))) float floatx4;

static __device__ __forceinline__ unsigned short f2bf(float f) {
    union { float f; unsigned int u; } v; v.f = f;
    unsigned int u = v.u;
    return (unsigned short)((u + 0x7FFFu + ((u >> 16) & 1u)) >> 16);   // RNE
}
static __device__ __forceinline__ float bf2f(unsigned short u) {
    union { unsigned int u; float f; } v; v.u = ((unsigned int)u) << 16; return v.f;
}
static __device__ __forceinline__ float bf2fs(short s) { return bf2f((unsigned short)s); }

// ---------------------------------------------------------------------------
// One-shot weight prep, all f32 [K][N] -> bf16 [N][K] at fixed slots:
//   val[0,65536) oa[65536,163840) (off rows 0..255 + attn rows 256..383)
//   out[163840,229376) ff1[229376,491520) ff2[491520,753664)
// plus bias_oa[384] floats (b_off ++ b_attn). Grid 2946x256.
// ---------------------------------------------------------------------------
__global__ __launch_bounds__(256) void prep_weights(
    const float* __restrict__ Wv, const float* __restrict__ Wo,
    const float* __restrict__ Wa, const float* __restrict__ Wu,
    const float* __restrict__ W1, const float* __restrict__ W2,
    const float* __restrict__ bo, const float* __restrict__ ba,
    unsigned short* __restrict__ wt, float* __restrict__ bias_oa)
{
    int idx = blockIdx.x * 256 + threadIdx.x;
    if (idx >= 754048) return;
    if (idx >= 753664) {               // bias concat
        int j = idx - 753664;
        bias_oa[j] = (j < 256) ? bo[j] : ba[j - 256];
        return;
    }
    float src;
    if (idx < 65536) {
        int r = idx; src = Wv[(size_t)(r & 255) * 256 + (r >> 8)];
    } else if (idx < 163840) {
        int r = idx - 65536; int n = r >> 8, k = r & 255;
        src = (n < 256) ? Wo[(size_t)k * 256 + n] : Wa[(size_t)k * 128 + (n - 256)];
    } else if (idx < 229376) {
        int r = idx - 163840; src = Wu[(size_t)(r & 255) * 256 + (r >> 8)];
    } else if (idx < 491520) {
        int r = idx - 229376; src = W1[(size_t)(r & 255) * 1024 + (r >> 8)];
    } else {
        int r = idx - 491520; src = W2[(size_t)(r & 1023) * 256 + (r >> 10)];
    }
    wt[idx] = f2bf(src);
}

// ---------------------------------------------------------------------------
// Reg-staged MFMA GEMM, padded LDS (conflict-free), 4 waves (2x2), BK=64.
// 64x64 tiles -> 18.4 KB LDS -> ~8 blocks/CU resident.
// SWZ=1: XCD-aware bijective remap (m204) + bn-fast tile order.
// Used for: val-proj, oa-proj (f32 A) and FF1 (bf16 A).
// ---------------------------------------------------------------------------
template<int AF32, int BM, int BN, int SPLITK, int RELU, int SWZ>
__global__ __launch_bounds__(256) void gemm_rs(
    const void* __restrict__ Av, const unsigned short* __restrict__ Bt,
    const float* __restrict__ bias,
    float* __restrict__ C, unsigned short* __restrict__ Cbf,
    int M, int N, int K)
{
    constexpr int AI = BM / 32;
    constexpr int BI = BN / 32;
    constexpr int FM = BM / 32;
    constexpr int FN = BN / 32;

    __shared__ short As[BM][72];
    __shared__ short Bs[BN][72];

    const int tid  = threadIdx.x;
    const int wave = tid >> 6;
    const int lane = tid & 63;
    const int ntiles = N / BN;

    int wgid;
    if (SWZ) {
        const int nwg = gridDim.x;
        const int xcd = blockIdx.x & 7;
        const int t   = blockIdx.x >> 3;
        const int q = nwg >> 3, r = nwg & 7;
        wgid = (xcd < r ? xcd * (q + 1) : r * (q + 1) + (xcd - r) * q) + t;
    } else {
        wgid = blockIdx.x;
    }
    const int tpm = ntiles * SPLITK;
    const int bm  = wgid / tpm;
    const int rem = wgid % tpm;
    const int bn  = rem % ntiles;
    const int ks  = rem / ntiles;

    const int row0 = bm * BM;
    const int col0 = bn * BN;
    const int Kper = K / SPLITK;
    const int kbeg = ks * Kper;

    const int wm = (wave >> 1) * (BM / 2);
    const int wn = (wave & 1) * (BN / 2);

    floatx4 acc[FM][FN];
    #pragma unroll
    for (int i = 0; i < FM; ++i)
        #pragma unroll
        for (int j = 0; j < FN; ++j)
            acc[i][j] = (floatx4){0.f, 0.f, 0.f, 0.f};

    const int lr = tid >> 3;
    const int lc = tid & 7;

    for (int k0 = 0; k0 < Kper; k0 += 64) {
        #pragma unroll
        for (int i = 0; i < AI; ++i) {
            const int r = lr + i * 32;
            if (AF32) {
                const float* Af = (const float*)Av;
                const float4 v0 = *reinterpret_cast<const float4*>(
                    &Af[(size_t)(row0 + r) * K + kbeg + k0 + lc * 8]);
                const float4 v1 = *reinterpret_cast<const float4*>(
                    &Af[(size_t)(row0 + r) * K + kbeg + k0 + lc * 8 + 4]);
                short8 s;
                s[0] = (short)f2bf(v0.x); s[1] = (short)f2bf(v0.y);
                s[2] = (short)f2bf(v0.z); s[3] = (short)f2bf(v0.w);
                s[4] = (short)f2bf(v1.x); s[5] = (short)f2bf(v1.y);
                s[6] = (short)f2bf(v1.z); s[7] = (short)f2bf(v1.w);
                *reinterpret_cast<short8*>(&As[r][lc * 8]) = s;
            } else {
                const unsigned short* Ab = (const unsigned short*)Av;
                *reinterpret_cast<short8*>(&As[r][lc * 8]) =
                    *reinterpret_cast<const short8*>(
                        &Ab[(size_t)(row0 + r) * K + kbeg + k0 + lc * 8]);
            }
        }
        #pragma unroll
        for (int i = 0; i < BI; ++i) {
            const int r = lr + i * 32;
            *reinterpret_cast<short8*>(&Bs[r][lc * 8]) =
                *reinterpret_cast<const short8*>(
                    &Bt[(size_t)(col0 + r) * K + kbeg + k0 + lc * 8]);
        }
        __syncthreads();

        #pragma unroll
        for (int kk = 0; kk < 64; kk += 32) {
            short8 af[FM], bfr[FN];
            #pragma unroll
            for (int i = 0; i < FM; ++i)
                af[i] = *reinterpret_cast<const short8*>(
                    &As[wm + i * 16 + (lane & 15)][kk + (lane >> 4) * 8]);
            #pragma unroll
            for (int j = 0; j < FN; ++j)
                bfr[j] = *reinterpret_cast<const short8*>(
                    &Bs[wn + j * 16 + (lane & 15)][kk + (lane >> 4) * 8]);
            #pragma unroll
            for (int i = 0; i < FM; ++i)
                #pragma unroll
                for (int j = 0; j < FN; ++j)
                    acc[i][j] = __builtin_amdgcn_mfma_f32_16x16x32_bf16(
                        af[i], bfr[j], acc[i][j], 0, 0, 0);
        }
        __syncthreads();
    }

    float* Cp = C ? C + (size_t)ks * M * N : nullptr;
    const int rbase = row0 + wm + (lane >> 4) * 4;
    const int cbase = col0 + wn + (lane & 15);
    #pragma unroll
    for (int j = 0; j < FN; ++j) {
        const float bj = (SPLITK == 1 || ks == 0) ? bias[cbase + j * 16] : 0.f;
        #pragma unroll
        for (int i = 0; i < FM; ++i) {
            #pragma unroll
            for (int r = 0; r < 4; ++r) {
                float v = acc[i][j][r] + bj;
                if (RELU) v = fmaxf(v, 0.f);
                const size_t idx = (size_t)(rbase + i * 16 + r) * N + cbase + j * 16;
                if (Cp)  Cp[idx] = v;
                if (Cbf) Cbf[idx] = f2bf(v);
            }
        }
    }
}

// ---------------------------------------------------------------------------
// GEMM + fused LayerNorm (full-row tile): BM=32, BN=256 (whole feature dim),
// 4 waves (2x2), wave tile 16x128, BK=64. One block owns complete rows ->
// LN in epilogue: per-thread partials -> shfl over 16-lane col group ->
// cross-wn-wave LDS exchange -> normalize in-register -> store.
//   x = A@Bt^T + bias (+ res if PREADD);  y = LN(x)*g + beta (+ res if POSTADD)
// PREADD:  FF2+LN2 (res = qbuf, pre-add);  POSTADD: out-proj+LN1 (res = value).
// ---------------------------------------------------------------------------
template<int PREADD, int POSTADD>
__global__ __launch_bounds__(256) void gemm_ln(
    const unsigned short* __restrict__ A, const unsigned short* __restrict__ Bt,
    const float* __restrict__ bias, const float* __restrict__ res,
    const float* __restrict__ g, const float* __restrict__ bta,
    float* __restrict__ outf, unsigned short* __restrict__ outbf,
    int K)
{
    __shared__ short As[32][72];
    __shared__ short Bs[256][72];
    __shared__ float2 part[2][32];

    const int tid  = threadIdx.x;
    const int wave = tid >> 6;
    const int lane = tid & 63;
    const int row0 = blockIdx.x * 32;
    const int wm = (wave >> 1) * 16;    // 0 / 16
    const int wn = (wave & 1) * 128;    // 0 / 128

    floatx4 acc[8];
    #pragma unroll
    for (int j = 0; j < 8; ++j) acc[j] = (floatx4){0.f, 0.f, 0.f, 0.f};

    const int lr = tid >> 3;   // 0..31
    const int lc = tid & 7;

    for (int k0 = 0; k0 < K; k0 += 64) {
        *reinterpret_cast<short8*>(&As[lr][lc * 8]) =
            *reinterpret_cast<const short8*>(
                &A[(size_t)(row0 + lr) * K + k0 + lc * 8]);
        #pragma unroll
        for (int i = 0; i < 8; ++i) {
            const int r = lr + i * 32;
            *reinterpret_cast<short8*>(&Bs[r][lc * 8]) =
                *reinterpret_cast<const short8*>(
                    &Bt[(size_t)r * K + k0 + lc * 8]);
        }
        __syncthreads();

        #pragma unroll
        for (int kk = 0; kk < 64; kk += 32) {
            short8 af = *reinterpret_cast<const short8*>(
                &As[wm + (lane & 15)][kk + (lane >> 4) * 8]);
            short8 bfr[8];
            #pragma unroll
            for (int j = 0; j < 8; ++j)
                bfr[j] = *reinterpret_cast<const short8*>(
                    &Bs[wn + j * 16 + (lane & 15)][kk + (lane >> 4) * 8]);
            #pragma unroll
            for (int j = 0; j < 8; ++j)
                acc[j] = __builtin_amdgcn_mfma_f32_16x16x32_bf16(
                    af, bfr[j], acc[j], 0, 0, 0);
        }
        __syncthreads();
    }

    // ---- epilogue: bias (+pre-add), row stats, LN, (+post-add), store ----
    const int rl = wm + (lane >> 4) * 4;   // local row base (thread owns rl..rl+3)
    const int cb = wn + (lane & 15);       // local col base (8 cols: cb + j*16)

    float v[8][4];
    #pragma unroll
    for (int j = 0; j < 8; ++j) {
        const float bj = bias[cb + j * 16];
        #pragma unroll
        for (int r = 0; r < 4; ++r) v[j][r] = acc[j][r] + bj;
    }
    if (PREADD) {
        #pragma unroll
        for (int j = 0; j < 8; ++j)
            #pragma unroll
            for (int r = 0; r < 4; ++r)
                v[j][r] += res[(size_t)(row0 + rl + r) * 256 + cb + j * 16];
    }

    float s1[4] = {0.f, 0.f, 0.f, 0.f}, s2[4] = {0.f, 0.f, 0.f, 0.f};
    #pragma unroll
    for (int j = 0; j < 8; ++j)
        #pragma unroll
        for (int r = 0; r < 4; ++r) {
            s1[r] += v[j][r];
            s2[r] += v[j][r] * v[j][r];
        }
    #pragma unroll
    for (int st = 1; st < 16; st <<= 1)
        #pragma unroll
        for (int r = 0; r < 4; ++r) {
            s1[r] += __shfl_xor(s1[r], st);
            s2[r] += __shfl_xor(s2[r], st);
        }
    if ((lane & 15) == 0) {
        #pragma unroll
        for (int r = 0; r < 4; ++r)
            part[wave & 1][rl + r] = (float2){s1[r], s2[r]};
    }
    __syncthreads();

    float mu[4], rstd[4];
    #pragma unroll
    for (int r = 0; r < 4; ++r) {
        const float2 p0 = part[0][rl + r];
        const float2 p1 = part[1][rl + r];
        const float t1 = p0.x + p1.x;
        const float t2 = p0.y + p1.y;
        mu[r] = t1 * (1.f / 256.f);
        rstd[r] = rsqrtf(t2 * (1.f / 256.f) - mu[r] * mu[r] + 1e-5f);
    }

    #pragma unroll
    for (int j = 0; j < 8; ++j) {
        const float gg = g[cb + j * 16];
        const float bb = bta[cb + j * 16];
        #pragma unroll
        for (int r = 0; r < 4; ++r) {
            const size_t idx = (size_t)(row0 + rl + r) * 256 + cb + j * 16;
            float o = (v[j][r] - mu[r]) * rstd[r] * gg + bb;
            if (POSTADD) o += res[idx];
            outf[idx] = o;
            if (outbf) outbf[idx] = f2bf(o);
        }
    }
}

// ---------------------------------------------------------------------------
// Deformable sampling + fused softmax, 2-phase LDS-staged (R12 optimum).
// ---------------------------------------------------------------------------
__global__ __launch_bounds__(256) void msda_sample(
    const unsigned short* __restrict__ vproj,
    const unsigned short* __restrict__ oa,
    const float* __restrict__ refs,
    unsigned short* __restrict__ outbf)
{
    __shared__ uint4 meta[64][33];

    const int tid = threadIdx.x;
    const int ul  = tid >> 2;
    const int u   = (blockIdx.x << 6) + ul;
    const int h   = u & 7;
    const int bq  = u >> 3;

    {
        const int l   = tid & 3;
        const int sl  = 6 - l;
        const int Nl  = 1 << sl;
        const int msk = Nl - 1;
        const int lsi = (l == 0) ? 0 : (l == 1) ? 4096 : (l == 2) ? 5120 : 5376;

        const size_t oabase = (size_t)bq * 384;
        const short8  offv = *reinterpret_cast<const short8*>(oa + oabase + h * 32 + l * 8);
        const ushort4 lgu  = *reinterpret_cast<const ushort4*>(oa + oabase + 256 + h * 16 + l * 4);
        const float2  rr   = *reinterpret_cast<const float2*>(refs + (size_t)bq * 8 + l * 2);

        float lg0 = bf2f(lgu.x), lg1 = bf2f(lgu.y), lg2 = bf2f(lgu.z), lg3 = bf2f(lgu.w);
        float m = fmaxf(fmaxf(lg0, lg1), fmaxf(lg2, lg3));
        m = fmaxf(m, __shfl_xor(m, 1));
        m = fmaxf(m, __shfl_xor(m, 2));
        float e0 = __expf(lg0 - m), e1 = __expf(lg1 - m),
              e2 = __expf(lg2 - m), e3 = __expf(lg3 - m);
        float s = e0 + e1 + e2 + e3;
        s += __shfl_xor(s, 1);
        s += __shfl_xor(s, 2);
        const float inv = 1.f / s;
        const float aw4[4] = {e0 * inv, e1 * inv, e2 * inv, e3 * inv};

        const float Nf = (float)Nl;
        #pragma unroll
        for (int p = 0; p < 4; ++p) {
            const float ox = bf2fs(offv[p * 2 + 0]);
            const float oy = bf2fs(offv[p * 2 + 1]);
            const float aw = aw4[p];
            const float x = fmaf(rr.x, Nf, ox) - 0.5f;
            const float y = fmaf(rr.y, Nf, oy) - 0.5f;
            const float xf = floorf(x), yf = floorf(y);
            const float tx = x - xf, ty = y - yf;
            const int xi = (int)xf, yi = (int)yf;
            const bool x0v = (unsigned)xi < (unsigned)Nl;
            const bool x1v = (unsigned)(xi + 1) < (unsigned)Nl;
            const bool y0v = (unsigned)yi < (unsigned)Nl;
            const bool y1v = (unsigned)(yi + 1) < (unsigned)Nl;
            const float w0x = (1.f - tx) * aw, w1x = tx * aw;
            const int xm0 = xi & msk, xm1 = (xi + 1) & msk;
            const int ym0 = (yi & msk) << sl, ym1 = ((yi + 1) & msk) << sl;
            uint4 m0, m1;
            m0.x = (unsigned)((lsi + (ym0 | xm0)) << 9);
            m0.y = __float_as_uint((x0v & y0v) ? w0x * (1.f - ty) : 0.f);
            m0.z = (unsigned)((lsi + (ym0 | xm1)) << 9);
            m0.w = __float_as_uint((x1v & y0v) ? w1x * (1.f - ty) : 0.f);
            m1.x = (unsigned)((lsi + (ym1 | xm0)) << 9);
            m1.y = __float_as_uint((x0v & y1v) ? w0x * ty : 0.f);
            m1.z = (unsigned)((lsi + (ym1 | xm1)) << 9);
            m1.w = __float_as_uint((x1v & y1v) ? w1x * ty : 0.f);
            meta[ul][l * 8 + p * 2 + 0] = m0;
            meta[ul][l * 8 + p * 2 + 1] = m1;
        }
    }
    __syncthreads();

    const int c = tid & 3;
    const int b = bq / LVTOT;
    const unsigned short* vb = vproj + (size_t)b * (LVTOT * 256) + h * 32 + c * 8;

    float acc[8] = {0.f, 0.f, 0.f, 0.f, 0.f, 0.f, 0.f, 0.f};
    #pragma unroll 4
    for (int j = 0; j < 32; ++j) {
        const uint4 mt = meta[ul][j];
        const uint4 g0 = *reinterpret_cast<const uint4*>((const char*)vb + mt.x);
        const uint4 g1 = *reinterpret_cast<const uint4*>((const char*)vb + mt.z);
        const float w0 = __uint_as_float(mt.y);
        const float w1 = __uint_as_float(mt.w);
        #pragma unroll
        for (int d = 0; d < 4; ++d) {
            const unsigned u0 = (&g0.x)[d];
            acc[2 * d]     = fmaf(w0, __uint_as_float(u0 << 16), acc[2 * d]);
            acc[2 * d + 1] = fmaf(w0, __uint_as_float(u0 & 0xffff0000u), acc[2 * d + 1]);
        }
        #pragma unroll
        for (int d = 0; d < 4; ++d) {
            const unsigned u1 = (&g1.x)[d];
            acc[2 * d]     = fmaf(w1, __uint_as_float(u1 << 16), acc[2 * d]);
            acc[2 * d + 1] = fmaf(w1, __uint_as_float(u1 & 0xffff0000u), acc[2 * d + 1]);
        }
    }

    uint4 ov;
    ov.x = (unsigned)f2bf(acc[0]) | ((unsigned)f2bf(acc[1]) << 16);
    ov.y = (unsigned)f2bf(acc[2]) | ((unsigned)f2bf(acc[3]) << 16);
    ov.z = (unsigned)f2bf(acc[4]) | ((unsigned)f2bf(acc[5]) << 16);
    ov.w = (unsigned)f2bf(acc[6]) | ((unsigned)f2bf(acc[7]) << 16);
    *reinterpret_cast<uint4*>(outbf + (size_t)bq * 256 + h * 32 + c * 8) = ov;
}

// ---------------------------------------------------------------------------
extern "C" void kernel_launch(void* const* d_in, const int* in_sizes, int n_in,
                              void* d_out, int out_size, void* d_ws, size_t ws_size,
                              hipStream_t stream)
{
    const float* query  = (const float*)d_in[0];
    const float* refs   = (const float*)d_in[1];
    const float* value  = (const float*)d_in[2];
    const float* W_off  = (const float*)d_in[5];
    const float* b_off  = (const float*)d_in[6];
    const float* W_attn = (const float*)d_in[7];
    const float* b_attn = (const float*)d_in[8];
    const float* W_val  = (const float*)d_in[9];
    const float* b_val  = (const float*)d_in[10];
    const float* W_out  = (const float*)d_in[11];
    const float* b_out  = (const float*)d_in[12];
    const float* ln1g   = (const float*)d_in[13];
    const float* ln1b   = (const float*)d_in[14];
    const float* ln2g   = (const float*)d_in[15];
    const float* ln2b   = (const float*)d_in[16];
    const float* W_ff1  = (const float*)d_in[17];
    const float* b_ff1  = (const float*)d_in[18];
    const float* W_ff2  = (const float*)d_in[19];
    const float* b_ff2  = (const float*)d_in[20];
    float* out = (float*)d_out;
    float* ws  = (float*)d_ws;

    const size_t R = (size_t)MROWS * 256;   // 5,570,560 floats
    // Workspace (float offsets), lifetime-reused:
    unsigned short* wt_base = (unsigned short*)ws;         // 753,664 bf16
    float* bias_oa = ws + 376832;                          // 384 (pad to 512)
    const size_t base0 = 377344;
    unsigned short* oa_bf    = (unsigned short*)(ws + base0);              // 0.75R fl
    unsigned short* vproj_bf = (unsigned short*)(ws + base0 + 3 * R / 4);  // 0.5R fl
    unsigned short* msda_bf  = (unsigned short*)(ws + base0 + 5 * R / 4);  // 0.5R fl
    // f1 pad: [base0+1.75R, base0+2R)
    float* qbuf = ws + base0 + 2 * R;                       // R
    unsigned short* qbuf_bf = (unsigned short*)(ws + base0 + 3 * R);       // 0.5R fl
    unsigned short* f1_bf = oa_bf;   // spans [base0, base0+2R) over dead regions

    unsigned short* wt_val = wt_base;
    unsigned short* wt_oa  = wt_base + 65536;
    unsigned short* wt_out = wt_base + 163840;
    unsigned short* wt_ff1 = wt_base + 229376;
    unsigned short* wt_ff2 = wt_base + 491520;

    const dim3 blk(256);
    const int mt64 = MROWS / 64;    // 340
    const int mt32 = MROWS / 32;    // 680

    // 0: weight prep
    prep_weights<<<dim3(2946), blk, 0, stream>>>(W_val, W_off, W_attn, W_out,
                                                 W_ff1, W_ff2, b_off, b_attn,
                                                 wt_base, bias_oa);
    // 1: value projection (f32 A), 64x64 tiles -> 1360 blocks
    gemm_rs<1, 64, 64, 1, 0, 1><<<dim3(mt64 * 4), blk, 0, stream>>>(
        value, wt_val, b_val, nullptr, vproj_bf, MROWS, 256, 256);
    // 2: merged offsets+logits projection (f32 A), 64x64 -> 2040 blocks
    gemm_rs<1, 64, 64, 1, 0, 1><<<dim3(mt64 * 6), blk, 0, stream>>>(
        query, wt_oa, bias_oa, nullptr, oa_bf, MROWS, 384, 256);
    // 3: sampling (R12 config, 64 units/block -> 2720 blocks)
    msda_sample<<<dim3(MROWS * 8 / 64), blk, 0, stream>>>(vproj_bf, oa_bf, refs, msda_bf);
    // 4: out-proj + LN1 fused (full-row tile): q = value + LN(msda@Wout+b)
    gemm_ln<0, 1><<<dim3(mt32), blk, 0, stream>>>(
        msda_bf, wt_out, b_out, value, ln1g, ln1b, qbuf, qbuf_bf, 256);
    // 5: f1 = relu(q @ W_ff1), 64x64 -> 5440 blocks
    gemm_rs<0, 64, 64, 1, 1, 1><<<dim3(mt64 * 16), blk, 0, stream>>>(
        qbuf_bf, wt_ff1, b_ff1, nullptr, f1_bf, MROWS, 1024, 256);
    // 6: FF2 + LN2 fused: out = LN(qbuf + f1@Wff2 + b)
    gemm_ln<1, 0><<<dim3(mt32), blk, 0, stream>>>(
        f1_bf, wt_ff2, b_ff2, qbuf, ln2g, ln2b, out, nullptr, 1024);
}